// Round 2
// baseline (737.663 us; speedup 1.0000x reference)
//
#include <hip/hip_runtime.h>
#include <math.h>

#define DEV __device__ __forceinline__

typedef __attribute__((ext_vector_type(4))) float f32x4;
typedef __attribute__((ext_vector_type(4))) unsigned short u16x4;
typedef __attribute__((ext_vector_type(8))) unsigned short u16x8;
typedef __attribute__((ext_vector_type(8))) __bf16 bfv8;

DEV unsigned short f2bf(float f) {
  unsigned u = __builtin_bit_cast(unsigned, f);
  u = (u + 0x7FFFu + ((u >> 16) & 1u)) >> 16;
  return (unsigned short)u;
}
DEV float bf2f(unsigned short h) {
  unsigned u = ((unsigned)h) << 16;
  return __builtin_bit_cast(float, u);
}

DEV f32x4 mfma16(u16x8 a, u16x8 b, f32x4 c) {
  return __builtin_amdgcn_mfma_f32_16x16x32_bf16(
      __builtin_bit_cast(bfv8, a), __builtin_bit_cast(bfv8, b), c, 0, 0, 0);
}

// ---------------------------------------------------------------------------
// in_proj GEMM: [4096x2048] @ [2048x8512]; epilogue routes cols to
// zbf (bf16, 0..4095) / xbcraw (bf16, 4096..8447) / dtraw (f32, 8448..8511)
// ---------------------------------------------------------------------------
__global__ __launch_bounds__(256) void gemm_in(
    const float* __restrict__ A, const float* __restrict__ B,
    unsigned short* __restrict__ zbf, unsigned short* __restrict__ xbcraw,
    float* __restrict__ dtraw) {
  constexpr int N = 8512, K = 2048, BKP = 72;
  __shared__ unsigned short As[128 * BKP];
  __shared__ unsigned short Bs[128 * BKP];
  const int tid = threadIdx.x;
  const int lane = tid & 63, wid = tid >> 6;
  const int wm = wid >> 1, wn = wid & 1;
  const int l16 = lane & 15, lq = lane >> 4;
  const int m0 = blockIdx.y * 128, n0 = blockIdx.x * 128;

  f32x4 acc[4][4] = {};
  for (int k0 = 0; k0 < K; k0 += 64) {
    if (k0) __syncthreads();
#pragma unroll
    for (int it = 0; it < 8; ++it) {
      int r = it * 16 + (tid >> 4);
      int kk = (tid & 15) * 4;
      f32x4 v = *(const f32x4*)(A + (size_t)(m0 + r) * K + k0 + kk);
      u16x4 hh = {f2bf(v[0]), f2bf(v[1]), f2bf(v[2]), f2bf(v[3])};
      *(u16x4*)(&As[r * BKP + kk]) = hh;
    }
#pragma unroll
    for (int it = 0; it < 2; ++it) {
      int nb = tid & 31;
      int kb = it * 8 + (tid >> 5);
      int nn = n0 + nb * 4;
      int kk = k0 + kb * 4;
      f32x4 r0, r1, r2, r3;
      if (nn < N) {
        r0 = *(const f32x4*)(B + (size_t)(kk + 0) * N + nn);
        r1 = *(const f32x4*)(B + (size_t)(kk + 1) * N + nn);
        r2 = *(const f32x4*)(B + (size_t)(kk + 2) * N + nn);
        r3 = *(const f32x4*)(B + (size_t)(kk + 3) * N + nn);
      } else {
        r0 = (f32x4){0.f, 0.f, 0.f, 0.f};
        r1 = r0; r2 = r0; r3 = r0;
      }
#pragma unroll
      for (int j = 0; j < 4; ++j) {
        u16x4 hh = {f2bf(r0[j]), f2bf(r1[j]), f2bf(r2[j]), f2bf(r3[j])};
        *(u16x4*)(&Bs[(nb * 4 + j) * BKP + kb * 4]) = hh;
      }
    }
    __syncthreads();
#pragma unroll
    for (int k2 = 0; k2 < 2; ++k2) {
      u16x8 af[4], bfr[4];
#pragma unroll
      for (int i = 0; i < 4; ++i) {
        af[i] = *(const u16x8*)(&As[(wm * 64 + i * 16 + l16) * BKP + k2 * 32 + lq * 8]);
        bfr[i] = *(const u16x8*)(&Bs[(wn * 64 + i * 16 + l16) * BKP + k2 * 32 + lq * 8]);
      }
#pragma unroll
      for (int mi = 0; mi < 4; ++mi)
#pragma unroll
        for (int ni = 0; ni < 4; ++ni)
          acc[mi][ni] = mfma16(af[mi], bfr[ni], acc[mi][ni]);
    }
  }
#pragma unroll
  for (int mi = 0; mi < 4; ++mi) {
#pragma unroll
    for (int ni = 0; ni < 4; ++ni) {
#pragma unroll
      for (int r = 0; r < 4; ++r) {
        int row = m0 + wm * 64 + mi * 16 + lq * 4 + r;
        int col = n0 + wn * 64 + ni * 16 + l16;
        float v = acc[mi][ni][r];
        if (n0 < 4096) {
          zbf[(size_t)row * 4096 + col] = f2bf(v);
        } else if (n0 < 8448) {
          xbcraw[(size_t)row * 4352 + (col - 4096)] = f2bf(v);
        } else {
          int cc = wn * 64 + ni * 16 + l16;
          if (cc < 64) dtraw[(size_t)row * 64 + cc] = v;
        }
      }
    }
  }
}

// ---------------------------------------------------------------------------
// out_proj GEMM: y(bf16)[4096x4096] @ w_out[4096x2048] + resid -> out f32
// ---------------------------------------------------------------------------
__global__ __launch_bounds__(256) void gemm_out(
    const unsigned short* __restrict__ A, const float* __restrict__ B,
    float* __restrict__ C, const float* __restrict__ resid) {
  constexpr int N = 2048, K = 4096, BKP = 72;
  __shared__ unsigned short As[128 * BKP];
  __shared__ unsigned short Bs[128 * BKP];
  const int tid = threadIdx.x;
  const int lane = tid & 63, wid = tid >> 6;
  const int wm = wid >> 1, wn = wid & 1;
  const int l16 = lane & 15, lq = lane >> 4;
  const int m0 = blockIdx.y * 128, n0 = blockIdx.x * 128;

  f32x4 acc[4][4] = {};
  for (int k0 = 0; k0 < K; k0 += 64) {
    if (k0) __syncthreads();
#pragma unroll
    for (int it = 0; it < 4; ++it) {
      int r = it * 32 + (tid >> 3);
      int kk = (tid & 7) * 8;
      u16x8 v = *(const u16x8*)(A + (size_t)(m0 + r) * K + k0 + kk);
      *(u16x8*)(&As[r * BKP + kk]) = v;
    }
#pragma unroll
    for (int it = 0; it < 2; ++it) {
      int nb = tid & 31;
      int kb = it * 8 + (tid >> 5);
      int nn = n0 + nb * 4;
      int kk = k0 + kb * 4;
      f32x4 r0 = *(const f32x4*)(B + (size_t)(kk + 0) * N + nn);
      f32x4 r1 = *(const f32x4*)(B + (size_t)(kk + 1) * N + nn);
      f32x4 r2 = *(const f32x4*)(B + (size_t)(kk + 2) * N + nn);
      f32x4 r3 = *(const f32x4*)(B + (size_t)(kk + 3) * N + nn);
#pragma unroll
      for (int j = 0; j < 4; ++j) {
        u16x4 hh = {f2bf(r0[j]), f2bf(r1[j]), f2bf(r2[j]), f2bf(r3[j])};
        *(u16x4*)(&Bs[(nb * 4 + j) * BKP + kb * 4]) = hh;
      }
    }
    __syncthreads();
#pragma unroll
    for (int k2 = 0; k2 < 2; ++k2) {
      u16x8 af[4], bfr[4];
#pragma unroll
      for (int i = 0; i < 4; ++i) {
        af[i] = *(const u16x8*)(&As[(wm * 64 + i * 16 + l16) * BKP + k2 * 32 + lq * 8]);
        bfr[i] = *(const u16x8*)(&Bs[(wn * 64 + i * 16 + l16) * BKP + k2 * 32 + lq * 8]);
      }
#pragma unroll
      for (int mi = 0; mi < 4; ++mi)
#pragma unroll
        for (int ni = 0; ni < 4; ++ni)
          acc[mi][ni] = mfma16(af[mi], bfr[ni], acc[mi][ni]);
    }
  }
#pragma unroll
  for (int mi = 0; mi < 4; ++mi)
#pragma unroll
    for (int ni = 0; ni < 4; ++ni) {
      int col = n0 + wn * 64 + ni * 16 + l16;
#pragma unroll
      for (int r = 0; r < 4; ++r) {
        int row = m0 + wm * 64 + mi * 16 + lq * 4 + r;
        size_t idx = (size_t)row * N + col;
        C[idx] = acc[mi][ni][r] + resid[idx];
      }
    }
}

// ---------------------------------------------------------------------------
// Depthwise causal conv (4 taps) + bias + SiLU, bf16 in/out
// ---------------------------------------------------------------------------
__global__ __launch_bounds__(256) void conv_kernel(
    const unsigned short* __restrict__ raw, const float* __restrict__ cw,
    const float* __restrict__ cb, unsigned short* __restrict__ xbc) {
  const int ch = blockIdx.x * 256 + threadIdx.x;  // 0..4351
  const int row = blockIdx.y;                     // 0..4095
  const int l = row & 2047;
  float acc = cb[ch];
#pragma unroll
  for (int k = 0; k < 4; ++k) {
    int ls = l - 3 + k;
    if (ls >= 0)
      acc += cw[ch * 4 + k] * bf2f(raw[(size_t)(row - 3 + k) * 4352 + ch]);
  }
  float s = acc / (1.0f + __expf(-acc));
  xbc[(size_t)row * 4352 + ch] = f2bf(s);
}

// ---------------------------------------------------------------------------
// dt softplus (in place) + per-chunk cumsum of dt*(-exp(A_log))
// ---------------------------------------------------------------------------
__global__ __launch_bounds__(256) void dt_kernel(
    float* __restrict__ dtb, const float* __restrict__ dt_bias,
    const float* __restrict__ A_log, float* __restrict__ Acs) {
  __shared__ float s[256];
  const int blk = blockIdx.x;
  const int c = blk & 7, h = (blk >> 3) & 63, b = blk >> 9;
  const int t = threadIdx.x;
  const int row = b * 2048 + c * 256 + t;
  float xv = dtb[(size_t)row * 64 + h] + dt_bias[h];
  float dt = (xv > 20.0f) ? xv : log1pf(__expf(xv));
  dtb[(size_t)row * 64 + h] = dt;
  float a = dt * (-__expf(A_log[h]));
  s[t] = a;
  __syncthreads();
  for (int off = 1; off < 256; off <<= 1) {
    float v = (t >= off) ? s[t - off] : 0.0f;
    __syncthreads();
    s[t] += v;
    __syncthreads();
  }
  Acs[((size_t)((b * 64 + h) * 8 + c)) * 256 + t] = s[t];
}

// ---------------------------------------------------------------------------
// G[bc][i][j] = sum_n Cm[i][n]*Bm[j][n] (head-independent)
// ---------------------------------------------------------------------------
__global__ __launch_bounds__(256) void g_kernel(
    const unsigned short* __restrict__ xbc, float* __restrict__ G) {
  const int bc = blockIdx.y;
  const int i0 = (blockIdx.x >> 2) * 64, j0 = (blockIdx.x & 3) * 64;
  const int tid = threadIdx.x;
  const int lane = tid & 63, w = tid >> 6;
  const int l16 = lane & 15, lq = lane >> 4;
  const unsigned short* base = xbc + (size_t)bc * 256 * 4352;
  f32x4 acc[4] = {};
#pragma unroll
  for (int ks = 0; ks < 4; ++ks) {
    int nb = ks * 32 + lq * 8;
    u16x8 af = *(const u16x8*)(base + (size_t)(i0 + w * 16 + l16) * 4352 + 4224 + nb);
#pragma unroll
    for (int jf = 0; jf < 4; ++jf) {
      u16x8 bb = *(const u16x8*)(base + (size_t)(j0 + jf * 16 + l16) * 4352 + 4096 + nb);
      acc[jf] = mfma16(af, bb, acc[jf]);
    }
  }
  float* Gt = G + (size_t)bc * 65536;
#pragma unroll
  for (int jf = 0; jf < 4; ++jf)
#pragma unroll
    for (int r = 0; r < 4; ++r)
      Gt[(i0 + w * 16 + lq * 4 + r) * 256 + j0 + jf * 16 + l16] = acc[jf][r];
}

// ---------------------------------------------------------------------------
// Per-chunk states: states[p][n] (bf16) = sum_t Bm[t][n]*decay(t)*X[t][p]
// 512 threads / 8 waves; wave w owns n-rows [w*16, w*16+16)
// ---------------------------------------------------------------------------
__global__ __launch_bounds__(512) void ssd_states(
    const unsigned short* __restrict__ xbc, const float* __restrict__ dtb,
    const float* __restrict__ Acs, unsigned short* __restrict__ statesb) {
  __shared__ unsigned short Xt[64 * 264];
  __shared__ unsigned short BmT[128 * 72];
  __shared__ float As_s[256];
  const int h = blockIdx.x, c = blockIdx.y, b = blockIdx.z;
  const int tid = threadIdx.x;
  const int lane = tid & 63, w = tid >> 6;
  const int l16 = lane & 15, lq = lane >> 4;
  const int row0 = b * 2048 + c * 256;

  if (tid < 256) As_s[tid] = Acs[((size_t)((b * 64 + h) * 8 + c)) * 256 + tid];
  // Xt[p][t] = xh[t][p]*dt[t]
#pragma unroll
  for (int it = 0; it < 2; ++it) {
    int pb = tid & 15;
    int tb = it * 32 + (tid >> 4);
    float rr[4][4];
#pragma unroll
    for (int i = 0; i < 4; ++i) {
      int row = row0 + tb * 4 + i;
      u16x4 v = *(const u16x4*)(xbc + (size_t)row * 4352 + h * 64 + pb * 4);
      float dtv = dtb[(size_t)row * 64 + h];
#pragma unroll
      for (int j = 0; j < 4; ++j) rr[i][j] = bf2f(v[j]) * dtv;
    }
#pragma unroll
    for (int j = 0; j < 4; ++j) {
      u16x4 hh = {f2bf(rr[0][j]), f2bf(rr[1][j]), f2bf(rr[2][j]), f2bf(rr[3][j])};
      *(u16x4*)(&Xt[(pb * 4 + j) * 264 + tb * 4]) = hh;
    }
  }
  __syncthreads();

  f32x4 accS[4] = {};
  const float Alast = As_s[255];
  for (int part = 0; part < 4; ++part) {
    if (part) __syncthreads();  // all BmT readers done
    {
      int nb = tid & 31;
      int tb = tid >> 5;  // 0..15
      float rr[4][4];
#pragma unroll
      for (int i = 0; i < 4; ++i) {
        int t = part * 64 + tb * 4 + i;
        int row = row0 + t;
        float dec = __expf(Alast - As_s[t]);
        u16x4 v = *(const u16x4*)(xbc + (size_t)row * 4352 + 4096 + nb * 4);
#pragma unroll
        for (int j = 0; j < 4; ++j) rr[i][j] = bf2f(v[j]) * dec;
      }
#pragma unroll
      for (int j = 0; j < 4; ++j) {
        u16x4 hh = {f2bf(rr[0][j]), f2bf(rr[1][j]), f2bf(rr[2][j]), f2bf(rr[3][j])};
        *(u16x4*)(&BmT[(nb * 4 + j) * 72 + tb * 4]) = hh;
      }
    }
    __syncthreads();
#pragma unroll
    for (int ks = 0; ks < 2; ++ks) {
      int toff = ks * 32 + lq * 8;
      u16x8 af = *(const u16x8*)(&BmT[(w * 16 + l16) * 72 + toff]);
#pragma unroll
      for (int pf = 0; pf < 4; ++pf) {
        u16x8 bfr = *(const u16x8*)(&Xt[(pf * 16 + l16) * 264 + part * 64 + toff]);
        accS[pf] = mfma16(af, bfr, accS[pf]);
      }
    }
  }
  unsigned short* Sp = statesb + (size_t)((b * 8 + c) * 64 + h) * 8192;
#pragma unroll
  for (int pf = 0; pf < 4; ++pf) {
    u16x4 hh = {f2bf(accS[pf][0]), f2bf(accS[pf][1]), f2bf(accS[pf][2]),
                f2bf(accS[pf][3])};
    *(u16x4*)(&Sp[(pf * 16 + l16) * 128 + w * 16 + lq * 4]) = hh;
  }
}

// ---------------------------------------------------------------------------
// Sequential chunk scan -> prefix states (bf16, [p][n]); grid (h, b)
// ---------------------------------------------------------------------------
__global__ __launch_bounds__(256) void scan_states(
    const unsigned short* __restrict__ statesb, const float* __restrict__ Acs,
    unsigned short* __restrict__ prefix) {
  const int h = blockIdx.x, b = blockIdx.y;
  const int tid = threadIdx.x;
  const int p = tid >> 2, nq = (tid & 3) * 32;
  float S[32];
#pragma unroll
  for (int i = 0; i < 32; ++i) S[i] = 0.0f;
  for (int cc = 0; cc < 8; ++cc) {
    size_t base = (size_t)((b * 8 + cc) * 64 + h) * 8192 + p * 128 + nq;
#pragma unroll
    for (int j = 0; j < 4; ++j) {
      u16x8 hh;
#pragma unroll
      for (int k = 0; k < 8; ++k) hh[k] = f2bf(S[j * 8 + k]);
      *(u16x8*)(prefix + base + j * 8) = hh;
    }
    float eAl = __expf(Acs[((size_t)((b * 64 + h) * 8 + cc)) * 256 + 255]);
#pragma unroll
    for (int j = 0; j < 4; ++j) {
      u16x8 v = *(const u16x8*)(statesb + base + j * 8);
#pragma unroll
      for (int k = 0; k < 8; ++k) S[j * 8 + k] = eAl * S[j * 8 + k] + bf2f(v[k]);
    }
  }
}

// ---------------------------------------------------------------------------
// Fused Y: Y_diag (G.*L @ X) + Y_off (exp(Acs)*Cm @ P^T) + D*xh -> y bf16
// 512 threads / 8 waves; wave w owns t-rows [w*32, w*32+32)
// ---------------------------------------------------------------------------
__global__ __launch_bounds__(512) void ssd_main(
    const unsigned short* __restrict__ xbc, const float* __restrict__ dtb,
    const float* __restrict__ Acs, const float* __restrict__ G,
    const unsigned short* __restrict__ prefix, const float* __restrict__ Dv,
    unsigned short* __restrict__ y) {
  __shared__ unsigned short Xt[64 * 264];
  __shared__ float As_s[256];
  const int h = blockIdx.x, c = blockIdx.y, b = blockIdx.z;
  const int tid = threadIdx.x;
  const int lane = tid & 63, w = tid >> 6;
  const int l16 = lane & 15, lq = lane >> 4;
  const int row0 = b * 2048 + c * 256;

  if (tid < 256) As_s[tid] = Acs[((size_t)((b * 64 + h) * 8 + c)) * 256 + tid];
#pragma unroll
  for (int it = 0; it < 2; ++it) {
    int pb = tid & 15;
    int tb = it * 32 + (tid >> 4);
    float rr[4][4];
#pragma unroll
    for (int i = 0; i < 4; ++i) {
      int row = row0 + tb * 4 + i;
      u16x4 v = *(const u16x4*)(xbc + (size_t)row * 4352 + h * 64 + pb * 4);
      float dtv = dtb[(size_t)row * 64 + h];
#pragma unroll
      for (int j = 0; j < 4; ++j) rr[i][j] = bf2f(v[j]) * dtv;
    }
#pragma unroll
    for (int j = 0; j < 4; ++j) {
      u16x4 hh = {f2bf(rr[0][j]), f2bf(rr[1][j]), f2bf(rr[2][j]), f2bf(rr[3][j])};
      *(u16x4*)(&Xt[(pb * 4 + j) * 264 + tb * 4]) = hh;
    }
  }
  __syncthreads();

  f32x4 acc[2][4] = {};
  // Y_diag
  const float* Gt = G + (size_t)(b * 8 + c) * 65536;
  for (int ks = 0; ks < 8; ++ks) {
    const int tb = ks * 32 + lq * 8;
    u16x8 bfr[4];
#pragma unroll
    for (int pf = 0; pf < 4; ++pf)
      bfr[pf] = *(const u16x8*)(&Xt[(pf * 16 + l16) * 264 + tb]);
#pragma unroll
    for (int mf = 0; mf < 2; ++mf) {
      const int i = w * 32 + mf * 16 + l16;
      const float ai = As_s[i];
      const float* gp = Gt + i * 256 + tb;
      f32x4 g0 = *(const f32x4*)gp;
      f32x4 g1 = *(const f32x4*)(gp + 4);
      u16x8 af;
#pragma unroll
      for (int jj = 0; jj < 8; ++jj) {
        int j = tb + jj;
        float g = (jj < 4) ? g0[jj] : g1[jj - 4];
        float v = (i >= j) ? g * __expf(ai - As_s[j]) : 0.0f;
        af[jj] = f2bf(v);
      }
#pragma unroll
      for (int pf = 0; pf < 4; ++pf)
        acc[mf][pf] = mfma16(af, bfr[pf], acc[mf][pf]);
    }
  }
  // Y_off: A = exp(Acs[t]) * Cm[t][n], B = prefix[p][n]
  const unsigned short* Pf = prefix + (size_t)((b * 8 + c) * 64 + h) * 8192;
  for (int ks = 0; ks < 4; ++ks) {
    const int nb = ks * 32 + lq * 8;
    u16x8 bfr[4];
#pragma unroll
    for (int pf = 0; pf < 4; ++pf)
      bfr[pf] = *(const u16x8*)(Pf + (size_t)(pf * 16 + l16) * 128 + nb);
#pragma unroll
    for (int mf = 0; mf < 2; ++mf) {
      const int i = w * 32 + mf * 16 + l16;
      const float eAi = __expf(As_s[i]);
      u16x8 cv = *(const u16x8*)(xbc + (size_t)(row0 + i) * 4352 + 4224 + nb);
      u16x8 af;
#pragma unroll
      for (int jj = 0; jj < 8; ++jj) af[jj] = f2bf(bf2f(cv[jj]) * eAi);
#pragma unroll
      for (int pf = 0; pf < 4; ++pf)
        acc[mf][pf] = mfma16(af, bfr[pf], acc[mf][pf]);
    }
  }
  const float Dh = Dv[h];
#pragma unroll
  for (int mf = 0; mf < 2; ++mf) {
#pragma unroll
    for (int r = 0; r < 4; ++r) {
      int t = w * 32 + mf * 16 + lq * 4 + r;
      size_t row = (size_t)(row0 + t);
#pragma unroll
      for (int pf = 0; pf < 4; ++pf) {
        int p = pf * 16 + l16;
        float xh = bf2f(xbc[row * 4352 + h * 64 + p]);
        y[row * 4096 + h * 64 + p] = f2bf(acc[mf][pf][r] + Dh * xh);
      }
    }
  }
}

// ---------------------------------------------------------------------------
// In-place: y = rmsnorm(y * silu(z)) * norm_w  (bf16)
// ---------------------------------------------------------------------------
__global__ __launch_bounds__(256) void norm_kernel(
    unsigned short* __restrict__ y, const unsigned short* __restrict__ zbf,
    const float* __restrict__ nw) {
  const int row = blockIdx.x, tid = threadIdx.x;
  unsigned short* yr = y + (size_t)row * 4096;
  const unsigned short* zr = zbf + (size_t)row * 4096;
  float vals[16];
  float ss = 0.0f;
#pragma unroll
  for (int i = 0; i < 2; ++i) {
    int cb = i * 2048 + tid * 8;
    u16x8 yv = *(const u16x8*)(yr + cb);
    u16x8 zv = *(const u16x8*)(zr + cb);
#pragma unroll
    for (int j = 0; j < 8; ++j) {
      float z = bf2f(zv[j]);
      float g = bf2f(yv[j]) * (z / (1.0f + __expf(-z)));
      vals[i * 8 + j] = g;
      ss += g * g;
    }
  }
#pragma unroll
  for (int off = 32; off > 0; off >>= 1) ss += __shfl_xor(ss, off, 64);
  __shared__ float red[4];
  if ((tid & 63) == 0) red[tid >> 6] = ss;
  __syncthreads();
  float tot = red[0] + red[1] + red[2] + red[3];
  float rr = rsqrtf(tot * (1.0f / 4096.0f) + 1e-5f);
#pragma unroll
  for (int i = 0; i < 2; ++i) {
    int cb = i * 2048 + tid * 8;
    f32x4 w0 = *(const f32x4*)(nw + cb);
    f32x4 w1 = *(const f32x4*)(nw + cb + 4);
    u16x8 o;
#pragma unroll
    for (int j = 0; j < 8; ++j) {
      float wv = (j < 4) ? w0[j] : w1[j - 4];
      o[j] = f2bf(vals[i * 8 + j] * rr * wv);
    }
    *(u16x8*)(yr + cb) = o;
  }
}

// ---------------------------------------------------------------------------
extern "C" void kernel_launch(void* const* d_in, const int* in_sizes, int n_in,
                              void* d_out, int out_size, void* d_ws,
                              size_t ws_size, hipStream_t stream) {
  const float* x = (const float*)d_in[0];
  const float* w_in = (const float*)d_in[1];
  const float* conv_w = (const float*)d_in[2];
  const float* conv_b = (const float*)d_in[3];
  const float* dt_bias = (const float*)d_in[4];
  const float* A_log = (const float*)d_in[5];
  const float* Dvec = (const float*)d_in[6];
  const float* norm_w = (const float*)d_in[7];
  const float* w_out = (const float*)d_in[8];
  float* out = (float*)d_out;

  char* w = (char*)d_ws;
  unsigned short* zbf = (unsigned short*)(w + 0);            // 4096*4096*2 = 33,554,432
  unsigned short* xbc = (unsigned short*)(w + 33554432);     // 4096*4352*2 = 35,651,584
  unsigned short* xbcraw = (unsigned short*)(w + 69206016);  // 35,651,584 (reused as prefix)
  float* dtb = (float*)(w + 104857600);                      // 4096*64*4 = 1,048,576
  float* Acs = (float*)(w + 105906176);                      // 1,048,576
  float* G = (float*)(w + 106954752);                        // 16*65536*4 = 4,194,304
  unsigned short* statesb = (unsigned short*)(w + 111149056);// 1024*8192*2 = 16,777,216
  unsigned short* y = (unsigned short*)(w + 127926272);      // 4096*4096*2 = 33,554,432
  unsigned short* prefix = xbcraw;                           // alias (dead after conv)

  gemm_in<<<dim3(67, 32), 256, 0, stream>>>(x, w_in, zbf, xbcraw, dtb);
  conv_kernel<<<dim3(17, 4096), 256, 0, stream>>>(xbcraw, conv_w, conv_b, xbc);
  dt_kernel<<<dim3(1024), 256, 0, stream>>>(dtb, dt_bias, A_log, Acs);
  g_kernel<<<dim3(16, 16), 256, 0, stream>>>(xbc, G);
  ssd_states<<<dim3(64, 8, 2), 512, 0, stream>>>(xbc, dtb, Acs, statesb);
  scan_states<<<dim3(64, 2), 256, 0, stream>>>(statesb, Acs, prefix);
  ssd_main<<<dim3(64, 8, 2), 512, 0, stream>>>(xbc, dtb, Acs, G, prefix, Dvec, y);
  norm_kernel<<<dim3(4096), 256, 0, stream>>>(y, zbf, norm_w);
  gemm_out<<<dim3(16, 32), 256, 0, stream>>>(y, w_out, out, x);
}

// Round 3
// 555.266 us; speedup vs baseline: 1.3285x; 1.3285x over previous
//
#include <hip/hip_runtime.h>
#include <math.h>

#define DEV __device__ __forceinline__

typedef __attribute__((ext_vector_type(4))) float f32x4;
typedef __attribute__((ext_vector_type(4))) unsigned short u16x4;
typedef __attribute__((ext_vector_type(8))) unsigned short u16x8;
typedef __attribute__((ext_vector_type(8))) __bf16 bfv8;

DEV unsigned short f2bf(float f) {
  unsigned u = __builtin_bit_cast(unsigned, f);
  u = (u + 0x7FFFu + ((u >> 16) & 1u)) >> 16;
  return (unsigned short)u;
}
DEV float bf2f(unsigned short h) {
  unsigned u = ((unsigned)h) << 16;
  return __builtin_bit_cast(float, u);
}

DEV f32x4 mfma16(u16x8 a, u16x8 b, f32x4 c) {
  return __builtin_amdgcn_mfma_f32_16x16x32_bf16(
      __builtin_bit_cast(bfv8, a), __builtin_bit_cast(bfv8, b), c, 0, 0, 0);
}

DEV void gload_lds16(const unsigned short* g, unsigned short* s) {
  __builtin_amdgcn_global_load_lds(
      (const __attribute__((address_space(1))) void*)g,
      (__attribute__((address_space(3))) void*)s, 16, 0, 0);
}

// ---------------------------------------------------------------------------
// x f32 -> bf16 (elementwise, 8/thread)
// ---------------------------------------------------------------------------
__global__ __launch_bounds__(256) void convert_bf16(
    const float* __restrict__ in, unsigned short* __restrict__ out) {
  const size_t i = ((size_t)blockIdx.x * 256 + threadIdx.x) * 8;
  f32x4 a = *(const f32x4*)(in + i);
  f32x4 b = *(const f32x4*)(in + i + 4);
  u16x8 o;
#pragma unroll
  for (int j = 0; j < 4; ++j) { o[j] = f2bf(a[j]); o[j + 4] = f2bf(b[j]); }
  *(u16x8*)(out + i) = o;
}

// ---------------------------------------------------------------------------
// transpose+convert: in[R][C] f32 -> out[Cpad][R] bf16 (rows c>=C zero-filled;
// Cpad = gridDim.x*64). 64x64 tiles via LDS.
// ---------------------------------------------------------------------------
__global__ __launch_bounds__(256) void transpose_conv(
    const float* __restrict__ in, unsigned short* __restrict__ out, int R,
    int C) {
  __shared__ __align__(16) unsigned short T[64][72];
  const int c0 = blockIdx.x * 64, r0 = blockIdx.y * 64;
  const int tid = threadIdx.x;
#pragma unroll
  for (int it = 0; it < 4; ++it) {
    int r = it * 16 + (tid >> 4);
    int c = (tid & 15) * 4;
    f32x4 v = {0.f, 0.f, 0.f, 0.f};
    if (c0 + c < C) v = *(const f32x4*)(in + (size_t)(r0 + r) * C + c0 + c);
#pragma unroll
    for (int j = 0; j < 4; ++j) T[c + j][r] = f2bf(v[j]);
  }
  __syncthreads();
  const int nr = tid >> 2, kc = (tid & 3) * 16;
  u16x8 a = *(const u16x8*)(&T[nr][kc]);
  u16x8 b = *(const u16x8*)(&T[nr][kc + 8]);
  unsigned short* o = out + (size_t)(c0 + nr) * R + r0 + kc;
  *(u16x8*)o = a;
  *(u16x8*)(o + 8) = b;
}

// ---------------------------------------------------------------------------
// bf16 GEMM, B pre-transposed: C[M,N] = A[M,K] @ Bt[N,K]^T
// 128x128 tile, BK=64, global_load_lds staging, linear LDS [128][64].
// MODE 0: in_proj routing epilogue; MODE 1: += resid, f32 out (N=2048).
// ---------------------------------------------------------------------------
template <int MODE>
__global__ __launch_bounds__(256) void gemm_bt(
    const unsigned short* __restrict__ A, const unsigned short* __restrict__ Bt,
    int K, unsigned short* __restrict__ o_z, unsigned short* __restrict__ o_xbc,
    float* __restrict__ o_dt, float* __restrict__ o_c,
    const float* __restrict__ resid) {
  __shared__ __align__(16) unsigned short As[128 * 64];
  __shared__ __align__(16) unsigned short Bs[128 * 64];
  const int tid = threadIdx.x;
  const int lane = tid & 63, wid = tid >> 6;
  const int wm = wid >> 1, wn = wid & 1;
  const int l16 = lane & 15, lq = lane >> 4;
  const int m0 = blockIdx.y * 128, n0 = blockIdx.x * 128;
  const int lr = lane >> 3;        // row within 8-row group
  const int lk = (lane & 7) * 8;   // k element offset (16B)

  f32x4 acc[4][4] = {};
  const unsigned short* Ap = A + (size_t)(m0 + wid * 32 + lr) * K + lk;
  const unsigned short* Bp = Bt + (size_t)(n0 + wid * 32 + lr) * K + lk;
  for (int k0 = 0; k0 < K; k0 += 64) {
    if (k0) __syncthreads();
#pragma unroll
    for (int it = 0; it < 4; ++it) {
      gload_lds16(Ap + (size_t)(it * 8) * K + k0, &As[(wid * 32 + it * 8) * 64]);
      gload_lds16(Bp + (size_t)(it * 8) * K + k0, &Bs[(wid * 32 + it * 8) * 64]);
    }
    __syncthreads();
#pragma unroll
    for (int k2 = 0; k2 < 2; ++k2) {
      u16x8 af[4], bfr[4];
#pragma unroll
      for (int i = 0; i < 4; ++i) {
        af[i] = *(const u16x8*)(&As[(wm * 64 + i * 16 + l16) * 64 + k2 * 32 + lq * 8]);
        bfr[i] = *(const u16x8*)(&Bs[(wn * 64 + i * 16 + l16) * 64 + k2 * 32 + lq * 8]);
      }
#pragma unroll
      for (int mi = 0; mi < 4; ++mi)
#pragma unroll
        for (int ni = 0; ni < 4; ++ni)
          acc[mi][ni] = mfma16(af[mi], bfr[ni], acc[mi][ni]);
    }
  }
#pragma unroll
  for (int mi = 0; mi < 4; ++mi) {
#pragma unroll
    for (int ni = 0; ni < 4; ++ni) {
      int col = n0 + wn * 64 + ni * 16 + l16;
#pragma unroll
      for (int r = 0; r < 4; ++r) {
        int row = m0 + wm * 64 + mi * 16 + lq * 4 + r;
        float v = acc[mi][ni][r];
        if constexpr (MODE == 0) {
          if (col < 4096) o_z[(size_t)row * 4096 + col] = f2bf(v);
          else if (col < 8448) o_xbc[(size_t)row * 4352 + (col - 4096)] = f2bf(v);
          else if (col < 8512) o_dt[(size_t)row * 64 + (col - 8448)] = v;
        } else {
          size_t idx = (size_t)row * 2048 + col;
          o_c[idx] = v + resid[idx];
        }
      }
    }
  }
}

// ---------------------------------------------------------------------------
// Depthwise causal conv (4 taps) + bias + SiLU, bf16 in/out, 4 ch/thread
// ---------------------------------------------------------------------------
__global__ __launch_bounds__(256) void conv_kernel(
    const unsigned short* __restrict__ raw, const float* __restrict__ cw,
    const float* __restrict__ cb, unsigned short* __restrict__ xbc) {
  const int ch4 = blockIdx.x * 256 + threadIdx.x;  // 0..1087
  if (ch4 >= 1088) return;
  const int ch = ch4 * 4;
  const int row = blockIdx.y;
  const int l = row & 2047;
  f32x4 acc = *(const f32x4*)(cb + ch);
  f32x4 w0 = *(const f32x4*)(cw + ch * 4);
  f32x4 w1 = *(const f32x4*)(cw + ch * 4 + 4);
  f32x4 w2 = *(const f32x4*)(cw + ch * 4 + 8);
  f32x4 w3 = *(const f32x4*)(cw + ch * 4 + 12);
#pragma unroll
  for (int k = 0; k < 4; ++k) {
    int ls = l - 3 + k;
    if (ls >= 0) {
      u16x4 v = *(const u16x4*)(raw + (size_t)(row - 3 + k) * 4352 + ch);
      acc[0] += w0[k] * bf2f(v[0]);
      acc[1] += w1[k] * bf2f(v[1]);
      acc[2] += w2[k] * bf2f(v[2]);
      acc[3] += w3[k] * bf2f(v[3]);
    }
  }
  u16x4 o;
#pragma unroll
  for (int j = 0; j < 4; ++j) {
    float s = acc[j] / (1.0f + __expf(-acc[j]));
    o[j] = f2bf(s);
  }
  *(u16x4*)(xbc + (size_t)row * 4352 + ch) = o;
}

// ---------------------------------------------------------------------------
// dt softplus (in place) + per-chunk cumsum of dt*(-exp(A_log))
// ---------------------------------------------------------------------------
__global__ __launch_bounds__(256) void dt_kernel(
    float* __restrict__ dtb, const float* __restrict__ dt_bias,
    const float* __restrict__ A_log, float* __restrict__ Acs) {
  __shared__ float s[256];
  const int blk = blockIdx.x;
  const int c = blk & 7, h = (blk >> 3) & 63, b = blk >> 9;
  const int t = threadIdx.x;
  const int row = b * 2048 + c * 256 + t;
  float xv = dtb[(size_t)row * 64 + h] + dt_bias[h];
  float dt = (xv > 20.0f) ? xv : log1pf(__expf(xv));
  dtb[(size_t)row * 64 + h] = dt;
  float a = dt * (-__expf(A_log[h]));
  s[t] = a;
  __syncthreads();
  for (int off = 1; off < 256; off <<= 1) {
    float v = (t >= off) ? s[t - off] : 0.0f;
    __syncthreads();
    s[t] += v;
    __syncthreads();
  }
  Acs[((size_t)((b * 64 + h) * 8 + c)) * 256 + t] = s[t];
}

// ---------------------------------------------------------------------------
// G[bc][i][j] = sum_n Cm[i][n]*Bm[j][n] (head-independent)
// ---------------------------------------------------------------------------
__global__ __launch_bounds__(256) void g_kernel(
    const unsigned short* __restrict__ xbc, float* __restrict__ G) {
  const int bc = blockIdx.y;
  const int i0 = (blockIdx.x >> 2) * 64, j0 = (blockIdx.x & 3) * 64;
  const int tid = threadIdx.x;
  const int lane = tid & 63, w = tid >> 6;
  const int l16 = lane & 15, lq = lane >> 4;
  const unsigned short* base = xbc + (size_t)bc * 256 * 4352;
  f32x4 acc[4] = {};
#pragma unroll
  for (int ks = 0; ks < 4; ++ks) {
    int nb = ks * 32 + lq * 8;
    u16x8 af = *(const u16x8*)(base + (size_t)(i0 + w * 16 + l16) * 4352 + 4224 + nb);
#pragma unroll
    for (int jf = 0; jf < 4; ++jf) {
      u16x8 bb = *(const u16x8*)(base + (size_t)(j0 + jf * 16 + l16) * 4352 + 4096 + nb);
      acc[jf] = mfma16(af, bb, acc[jf]);
    }
  }
  float* Gt = G + (size_t)bc * 65536;
#pragma unroll
  for (int jf = 0; jf < 4; ++jf)
#pragma unroll
    for (int r = 0; r < 4; ++r)
      Gt[(i0 + w * 16 + lq * 4 + r) * 256 + j0 + jf * 16 + l16] = acc[jf][r];
}

// ---------------------------------------------------------------------------
// Per-chunk states: states[p][n] (bf16) = sum_t Bm[t][n]*decay(t)*X[t][p]
// ---------------------------------------------------------------------------
__global__ __launch_bounds__(512) void ssd_states(
    const unsigned short* __restrict__ xbc, const float* __restrict__ dtb,
    const float* __restrict__ Acs, unsigned short* __restrict__ statesb) {
  __shared__ __align__(16) unsigned short Xt[64 * 264];
  __shared__ __align__(16) unsigned short BmT[128 * 72];
  __shared__ float As_s[256];
  const int h = blockIdx.x, c = blockIdx.y, b = blockIdx.z;
  const int tid = threadIdx.x;
  const int lane = tid & 63, w = tid >> 6;
  const int l16 = lane & 15, lq = lane >> 4;
  const int row0 = b * 2048 + c * 256;

  if (tid < 256) As_s[tid] = Acs[((size_t)((b * 64 + h) * 8 + c)) * 256 + tid];
#pragma unroll
  for (int it = 0; it < 2; ++it) {
    int pb = tid & 15;
    int tb = it * 32 + (tid >> 4);
    float rr[4][4];
#pragma unroll
    for (int i = 0; i < 4; ++i) {
      int row = row0 + tb * 4 + i;
      u16x4 v = *(const u16x4*)(xbc + (size_t)row * 4352 + h * 64 + pb * 4);
      float dtv = dtb[(size_t)row * 64 + h];
#pragma unroll
      for (int j = 0; j < 4; ++j) rr[i][j] = bf2f(v[j]) * dtv;
    }
#pragma unroll
    for (int j = 0; j < 4; ++j) {
      u16x4 hh = {f2bf(rr[0][j]), f2bf(rr[1][j]), f2bf(rr[2][j]), f2bf(rr[3][j])};
      *(u16x4*)(&Xt[(pb * 4 + j) * 264 + tb * 4]) = hh;
    }
  }
  __syncthreads();

  f32x4 accS[4] = {};
  const float Alast = As_s[255];
  for (int part = 0; part < 4; ++part) {
    if (part) __syncthreads();
    {
      int nb = tid & 31;
      int tb = tid >> 5;
      float rr[4][4];
#pragma unroll
      for (int i = 0; i < 4; ++i) {
        int t = part * 64 + tb * 4 + i;
        int row = row0 + t;
        float dec = __expf(Alast - As_s[t]);
        u16x4 v = *(const u16x4*)(xbc + (size_t)row * 4352 + 4096 + nb * 4);
#pragma unroll
        for (int j = 0; j < 4; ++j) rr[i][j] = bf2f(v[j]) * dec;
      }
#pragma unroll
      for (int j = 0; j < 4; ++j) {
        u16x4 hh = {f2bf(rr[0][j]), f2bf(rr[1][j]), f2bf(rr[2][j]), f2bf(rr[3][j])};
        *(u16x4*)(&BmT[(nb * 4 + j) * 72 + tb * 4]) = hh;
      }
    }
    __syncthreads();
#pragma unroll
    for (int ks = 0; ks < 2; ++ks) {
      int toff = ks * 32 + lq * 8;
      u16x8 af = *(const u16x8*)(&BmT[(w * 16 + l16) * 72 + toff]);
#pragma unroll
      for (int pf = 0; pf < 4; ++pf) {
        u16x8 bfr = *(const u16x8*)(&Xt[(pf * 16 + l16) * 264 + part * 64 + toff]);
        accS[pf] = mfma16(af, bfr, accS[pf]);
      }
    }
  }
  unsigned short* Sp = statesb + (size_t)((b * 8 + c) * 64 + h) * 8192;
#pragma unroll
  for (int pf = 0; pf < 4; ++pf) {
    u16x4 hh = {f2bf(accS[pf][0]), f2bf(accS[pf][1]), f2bf(accS[pf][2]),
                f2bf(accS[pf][3])};
    *(u16x4*)(&Sp[(pf * 16 + l16) * 128 + w * 16 + lq * 4]) = hh;
  }
}

// ---------------------------------------------------------------------------
// Sequential chunk scan -> prefix states (bf16, [p][n]); grid (h, b)
// ---------------------------------------------------------------------------
__global__ __launch_bounds__(256) void scan_states(
    const unsigned short* __restrict__ statesb, const float* __restrict__ Acs,
    unsigned short* __restrict__ prefix) {
  const int h = blockIdx.x, b = blockIdx.y;
  const int tid = threadIdx.x;
  const int p = tid >> 2, nq = (tid & 3) * 32;
  float S[32];
#pragma unroll
  for (int i = 0; i < 32; ++i) S[i] = 0.0f;
  for (int cc = 0; cc < 8; ++cc) {
    size_t base = (size_t)((b * 8 + cc) * 64 + h) * 8192 + p * 128 + nq;
#pragma unroll
    for (int j = 0; j < 4; ++j) {
      u16x8 hh;
#pragma unroll
      for (int k = 0; k < 8; ++k) hh[k] = f2bf(S[j * 8 + k]);
      *(u16x8*)(prefix + base + j * 8) = hh;
    }
    float eAl = __expf(Acs[((size_t)((b * 64 + h) * 8 + cc)) * 256 + 255]);
#pragma unroll
    for (int j = 0; j < 4; ++j) {
      u16x8 v = *(const u16x8*)(statesb + base + j * 8);
#pragma unroll
      for (int k = 0; k < 8; ++k) S[j * 8 + k] = eAl * S[j * 8 + k] + bf2f(v[k]);
    }
  }
}

// ---------------------------------------------------------------------------
// Fused Y: Y_diag (G.*L @ X) + Y_off (exp(Acs)*Cm @ P^T) + D*xh -> y bf16
// ---------------------------------------------------------------------------
__global__ __launch_bounds__(512) void ssd_main(
    const unsigned short* __restrict__ xbc, const float* __restrict__ dtb,
    const float* __restrict__ Acs, const float* __restrict__ G,
    const unsigned short* __restrict__ prefix, const float* __restrict__ Dv,
    unsigned short* __restrict__ y) {
  __shared__ __align__(16) unsigned short Xt[64 * 264];
  __shared__ float As_s[256];
  const int h = blockIdx.x, c = blockIdx.y, b = blockIdx.z;
  const int tid = threadIdx.x;
  const int lane = tid & 63, w = tid >> 6;
  const int l16 = lane & 15, lq = lane >> 4;
  const int row0 = b * 2048 + c * 256;

  if (tid < 256) As_s[tid] = Acs[((size_t)((b * 64 + h) * 8 + c)) * 256 + tid];
#pragma unroll
  for (int it = 0; it < 2; ++it) {
    int pb = tid & 15;
    int tb = it * 32 + (tid >> 4);
    float rr[4][4];
#pragma unroll
    for (int i = 0; i < 4; ++i) {
      int row = row0 + tb * 4 + i;
      u16x4 v = *(const u16x4*)(xbc + (size_t)row * 4352 + h * 64 + pb * 4);
      float dtv = dtb[(size_t)row * 64 + h];
#pragma unroll
      for (int j = 0; j < 4; ++j) rr[i][j] = bf2f(v[j]) * dtv;
    }
#pragma unroll
    for (int j = 0; j < 4; ++j) {
      u16x4 hh = {f2bf(rr[0][j]), f2bf(rr[1][j]), f2bf(rr[2][j]), f2bf(rr[3][j])};
      *(u16x4*)(&Xt[(pb * 4 + j) * 264 + tb * 4]) = hh;
    }
  }
  __syncthreads();

  f32x4 acc[2][4] = {};
  const float* Gt = G + (size_t)(b * 8 + c) * 65536;
  for (int ks = 0; ks < 8; ++ks) {
    const int tb = ks * 32 + lq * 8;
    u16x8 bfr[4];
#pragma unroll
    for (int pf = 0; pf < 4; ++pf)
      bfr[pf] = *(const u16x8*)(&Xt[(pf * 16 + l16) * 264 + tb]);
#pragma unroll
    for (int mf = 0; mf < 2; ++mf) {
      const int i = w * 32 + mf * 16 + l16;
      const float ai = As_s[i];
      const float* gp = Gt + i * 256 + tb;
      f32x4 g0 = *(const f32x4*)gp;
      f32x4 g1 = *(const f32x4*)(gp + 4);
      u16x8 af;
#pragma unroll
      for (int jj = 0; jj < 8; ++jj) {
        int j = tb + jj;
        float g = (jj < 4) ? g0[jj] : g1[jj - 4];
        float v = (i >= j) ? g * __expf(ai - As_s[j]) : 0.0f;
        af[jj] = f2bf(v);
      }
#pragma unroll
      for (int pf = 0; pf < 4; ++pf)
        acc[mf][pf] = mfma16(af, bfr[pf], acc[mf][pf]);
    }
  }
  const unsigned short* Pf = prefix + (size_t)((b * 8 + c) * 64 + h) * 8192;
  for (int ks = 0; ks < 4; ++ks) {
    const int nb = ks * 32 + lq * 8;
    u16x8 bfr[4];
#pragma unroll
    for (int pf = 0; pf < 4; ++pf)
      bfr[pf] = *(const u16x8*)(Pf + (size_t)(pf * 16 + l16) * 128 + nb);
#pragma unroll
    for (int mf = 0; mf < 2; ++mf) {
      const int i = w * 32 + mf * 16 + l16;
      const float eAi = __expf(As_s[i]);
      u16x8 cv = *(const u16x8*)(xbc + (size_t)(row0 + i) * 4352 + 4224 + nb);
      u16x8 af;
#pragma unroll
      for (int jj = 0; jj < 8; ++jj) af[jj] = f2bf(bf2f(cv[jj]) * eAi);
#pragma unroll
      for (int pf = 0; pf < 4; ++pf)
        acc[mf][pf] = mfma16(af, bfr[pf], acc[mf][pf]);
    }
  }
  const float Dh = Dv[h];
#pragma unroll
  for (int mf = 0; mf < 2; ++mf) {
#pragma unroll
    for (int r = 0; r < 4; ++r) {
      int t = w * 32 + mf * 16 + lq * 4 + r;
      size_t row = (size_t)(row0 + t);
#pragma unroll
      for (int pf = 0; pf < 4; ++pf) {
        int p = pf * 16 + l16;
        float xh = bf2f(xbc[row * 4352 + h * 64 + p]);
        y[row * 4096 + h * 64 + p] = f2bf(acc[mf][pf][r] + Dh * xh);
      }
    }
  }
}

// ---------------------------------------------------------------------------
// In-place: y = rmsnorm(y * silu(z)) * norm_w  (bf16)
// ---------------------------------------------------------------------------
__global__ __launch_bounds__(256) void norm_kernel(
    unsigned short* __restrict__ y, const unsigned short* __restrict__ zbf,
    const float* __restrict__ nw) {
  const int row = blockIdx.x, tid = threadIdx.x;
  unsigned short* yr = y + (size_t)row * 4096;
  const unsigned short* zr = zbf + (size_t)row * 4096;
  float vals[16];
  float ss = 0.0f;
#pragma unroll
  for (int i = 0; i < 2; ++i) {
    int cb = i * 2048 + tid * 8;
    u16x8 yv = *(const u16x8*)(yr + cb);
    u16x8 zv = *(const u16x8*)(zr + cb);
#pragma unroll
    for (int j = 0; j < 8; ++j) {
      float z = bf2f(zv[j]);
      float g = bf2f(yv[j]) * (z / (1.0f + __expf(-z)));
      vals[i * 8 + j] = g;
      ss += g * g;
    }
  }
#pragma unroll
  for (int off = 32; off > 0; off >>= 1) ss += __shfl_xor(ss, off, 64);
  __shared__ float red[4];
  if ((tid & 63) == 0) red[tid >> 6] = ss;
  __syncthreads();
  float tot = red[0] + red[1] + red[2] + red[3];
  float rr = rsqrtf(tot * (1.0f / 4096.0f) + 1e-5f);
#pragma unroll
  for (int i = 0; i < 2; ++i) {
    int cb = i * 2048 + tid * 8;
    f32x4 w0 = *(const f32x4*)(nw + cb);
    f32x4 w1 = *(const f32x4*)(nw + cb + 4);
    u16x8 o;
#pragma unroll
    for (int j = 0; j < 8; ++j) {
      float wv = (j < 4) ? w0[j] : w1[j - 4];
      o[j] = f2bf(vals[i * 8 + j] * rr * wv);
    }
    *(u16x8*)(yr + cb) = o;
  }
}

// ---------------------------------------------------------------------------
extern "C" void kernel_launch(void* const* d_in, const int* in_sizes, int n_in,
                              void* d_out, int out_size, void* d_ws,
                              size_t ws_size, hipStream_t stream) {
  const float* x = (const float*)d_in[0];
  const float* w_in = (const float*)d_in[1];
  const float* conv_w = (const float*)d_in[2];
  const float* conv_b = (const float*)d_in[3];
  const float* dt_bias = (const float*)d_in[4];
  const float* A_log = (const float*)d_in[5];
  const float* Dvec = (const float*)d_in[6];
  const float* norm_w = (const float*)d_in[7];
  const float* w_out = (const float*)d_in[8];
  float* out = (float*)d_out;

  char* w = (char*)d_ws;
  unsigned short* zbf = (unsigned short*)(w + 0);            // 33,554,432
  unsigned short* xbc = (unsigned short*)(w + 33554432);     // 35,651,584
  unsigned short* xbcraw = (unsigned short*)(w + 69206016);  // 35,651,584 (→prefix)
  float* dtb = (float*)(w + 104857600);                      // 1,048,576
  float* Acs = (float*)(w + 105906176);                      // 1,048,576
  float* G = (float*)(w + 106954752);                        // 4,194,304
  unsigned short* statesb = (unsigned short*)(w + 111149056);// 16,777,216
  unsigned short* y = (unsigned short*)(w + 127926272);      // 33,554,432
  // aliases (lifetimes disjoint, single stream):
  unsigned short* xbf = (unsigned short*)(w + 111149056);    // = statesb region
  unsigned short* w_inT = (unsigned short*)(w + 33554432);   // = xbc region (8576x2048)
  unsigned short* w_outT = (unsigned short*)(w + 33554432);  // = xbc region (2048x4096)
  unsigned short* prefix = xbcraw;

  convert_bf16<<<dim3(4096), 256, 0, stream>>>(x, xbf);
  transpose_conv<<<dim3(134, 32), 256, 0, stream>>>(w_in, w_inT, 2048, 8512);
  gemm_bt<0><<<dim3(67, 32), 256, 0, stream>>>(xbf, w_inT, 2048, zbf, xbcraw,
                                               dtb, nullptr, nullptr);
  conv_kernel<<<dim3(5, 4096), 256, 0, stream>>>(xbcraw, conv_w, conv_b, xbc);
  dt_kernel<<<dim3(1024), 256, 0, stream>>>(dtb, dt_bias, A_log, Acs);
  g_kernel<<<dim3(16, 16), 256, 0, stream>>>(xbc, G);
  ssd_states<<<dim3(64, 8, 2), 512, 0, stream>>>(xbc, dtb, Acs, statesb);
  scan_states<<<dim3(64, 2), 256, 0, stream>>>(statesb, Acs, prefix);
  ssd_main<<<dim3(64, 8, 2), 512, 0, stream>>>(xbc, dtb, Acs, G, prefix, Dvec, y);
  transpose_conv<<<dim3(32, 64), 256, 0, stream>>>(w_out, w_outT, 4096, 2048);
  norm_kernel<<<dim3(4096), 256, 0, stream>>>(y, zbf, norm_w);
  gemm_bt<1><<<dim3(16, 32), 256, 0, stream>>>(y, w_outT, 4096, nullptr,
                                               nullptr, nullptr, out, x);
}

// Round 4
// 553.094 us; speedup vs baseline: 1.3337x; 1.0039x over previous
//
#include <hip/hip_runtime.h>
#include <math.h>

#define DEV __device__ __forceinline__

typedef __attribute__((ext_vector_type(4))) float f32x4;
typedef __attribute__((ext_vector_type(4))) unsigned short u16x4;
typedef __attribute__((ext_vector_type(8))) unsigned short u16x8;
typedef __attribute__((ext_vector_type(8))) __bf16 bfv8;

DEV unsigned short f2bf(float f) {
  unsigned u = __builtin_bit_cast(unsigned, f);
  u = (u + 0x7FFFu + ((u >> 16) & 1u)) >> 16;
  return (unsigned short)u;
}
DEV float bf2f(unsigned short h) {
  unsigned u = ((unsigned)h) << 16;
  return __builtin_bit_cast(float, u);
}

DEV f32x4 mfma16(u16x8 a, u16x8 b, f32x4 c) {
  return __builtin_amdgcn_mfma_f32_16x16x32_bf16(
      __builtin_bit_cast(bfv8, a), __builtin_bit_cast(bfv8, b), c, 0, 0, 0);
}

DEV void gload_lds16(const unsigned short* g, unsigned short* s) {
  __builtin_amdgcn_global_load_lds(
      (const __attribute__((address_space(1))) void*)g,
      (__attribute__((address_space(3))) void*)s, 16, 0, 0);
}

template <int N>
DEV void vmcnt_wait() {
  if constexpr (N == 0) asm volatile("s_waitcnt vmcnt(0)" ::: "memory");
  else if constexpr (N == 3) asm volatile("s_waitcnt vmcnt(3)" ::: "memory");
  else if constexpr (N == 4) asm volatile("s_waitcnt vmcnt(4)" ::: "memory");
  else if constexpr (N == 6) asm volatile("s_waitcnt vmcnt(6)" ::: "memory");
  else if constexpr (N == 8) asm volatile("s_waitcnt vmcnt(8)" ::: "memory");
}

// ---------------------------------------------------------------------------
// Pipelined bf16 GEMM (counted-vmcnt, 3 LDS buffers, BK=32):
// C[M,N] = A[M,K] @ Bt[N,K]^T.  512 thr / 8 waves (2x4).
// MODE 0: in_proj routing epilogue; MODE 1: += resid -> f32 (N=2048).
// Both-sides XOR chunk swizzle (q ^= (row>>1)&3): linear LDS dest,
// pre-swizzled global source, swizzled ds_read -> 2-way (free) conflicts.
// ---------------------------------------------------------------------------
template <int BM, int BN, int MODE>
__global__ __launch_bounds__(512, 2) void gemm_p(
    const unsigned short* __restrict__ A, const unsigned short* __restrict__ Bt,
    int K, unsigned short* __restrict__ o_z, unsigned short* __restrict__ o_xbc,
    float* __restrict__ o_dt, float* __restrict__ o_c,
    const float* __restrict__ resid) {
  constexpr int LA = BM / 128, LB = BN / 128, L = LA + LB;
  constexpr int MF = BM / 32, NF = BN / 64;
  __shared__ __align__(16) unsigned short As[3][BM * 32];
  __shared__ __align__(16) unsigned short Bs[3][BN * 32];
  const int tid = threadIdx.x;
  const int lane = tid & 63, w = tid >> 6;
  const int l16 = lane & 15, lq = lane >> 4;
  const int wr = w >> 2, wc = w & 3;
  // XCD-aware bijective swizzle (grid divisible by 8)
  const int nwg = gridDim.x * gridDim.y;
  int lin = blockIdx.y * gridDim.x + blockIdx.x;
  lin = (lin & 7) * (nwg >> 3) + (lin >> 3);
  const int m0 = (lin / gridDim.x) * BM, n0 = (lin % gridDim.x) * BN;
  // staging: lane covers row rowbase+(lane>>2), chunk lane&3 (16B chunks)
  const int lrow = lane >> 2;
  const int gq = (lane & 3) ^ ((lrow >> 1) & 3);  // pre-swizzled source chunk
  // compute-side swizzled chunk
  const int cq = lq ^ ((l16 >> 1) & 3);

  f32x4 acc[MF][NF] = {};

#define STAGE(bi, kt)                                                         \
  {                                                                           \
    const int k0s = (kt) * 32 + gq * 8;                                       \
    _Pragma("unroll") for (int i = 0; i < LA; ++i) {                          \
      const int rb = (w + i * 8) * 16;                                        \
      gload_lds16(A + (size_t)(m0 + rb + lrow) * K + k0s, &As[bi][rb * 32]);  \
    }                                                                         \
    _Pragma("unroll") for (int i = 0; i < LB; ++i) {                          \
      const int rb = (w + i * 8) * 16;                                        \
      gload_lds16(Bt + (size_t)(n0 + rb + lrow) * K + k0s, &Bs[bi][rb * 32]); \
    }                                                                         \
  }

  auto compute = [&](int cb) {
    u16x8 af[MF], bfr[NF];
#pragma unroll
    for (int mf = 0; mf < MF; ++mf)
      af[mf] = *(const u16x8*)(&As[cb][(wr * (BM / 2) + mf * 16 + l16) * 32 + cq * 8]);
#pragma unroll
    for (int nf = 0; nf < NF; ++nf)
      bfr[nf] = *(const u16x8*)(&Bs[cb][(wc * (BN / 4) + nf * 16 + l16) * 32 + cq * 8]);
    __builtin_amdgcn_s_setprio(1);
#pragma unroll
    for (int mf = 0; mf < MF; ++mf)
#pragma unroll
      for (int nf = 0; nf < NF; ++nf)
        acc[mf][nf] = mfma16(af[mf], bfr[nf], acc[mf][nf]);
    __builtin_amdgcn_s_setprio(0);
  };

  const int nt = K / 32;
  STAGE(0, 0)
  STAGE(1, 1)
  int cb = 0;
  for (int t = 0; t < nt - 2; ++t) {
    int pb = cb + 2;
    if (pb >= 3) pb -= 3;
    STAGE(pb, t + 2)
    vmcnt_wait<2 * L>();
    __builtin_amdgcn_s_barrier();
    asm volatile("" ::: "memory");
    compute(cb);
    asm volatile("" ::: "memory");
    __builtin_amdgcn_s_barrier();
    ++cb;
    if (cb >= 3) cb = 0;
  }
  vmcnt_wait<L>();
  __builtin_amdgcn_s_barrier();
  asm volatile("" ::: "memory");
  compute(cb);
  ++cb;
  if (cb >= 3) cb = 0;
  vmcnt_wait<0>();
  __builtin_amdgcn_s_barrier();
  asm volatile("" ::: "memory");
  compute(cb);
#undef STAGE

#pragma unroll
  for (int mf = 0; mf < MF; ++mf) {
#pragma unroll
    for (int nf = 0; nf < NF; ++nf) {
      const int col = n0 + wc * (BN / 4) + nf * 16 + l16;
#pragma unroll
      for (int r = 0; r < 4; ++r) {
        const int row = m0 + wr * (BM / 2) + mf * 16 + lq * 4 + r;
        float v = acc[mf][nf][r];
        if constexpr (MODE == 0) {
          if (col < 4096) o_z[(size_t)row * 4096 + col] = f2bf(v);
          else if (col < 8448) o_xbc[(size_t)row * 4352 + (col - 4096)] = f2bf(v);
          else if (col < 8512) o_dt[(size_t)row * 64 + (col - 8448)] = v;
        } else {
          size_t idx = (size_t)row * 2048 + col;
          o_c[idx] = v + resid[idx];
        }
      }
    }
  }
}

// ---------------------------------------------------------------------------
// x f32 -> bf16 (elementwise, 8/thread)
// ---------------------------------------------------------------------------
__global__ __launch_bounds__(256) void convert_bf16(
    const float* __restrict__ in, unsigned short* __restrict__ out) {
  const size_t i = ((size_t)blockIdx.x * 256 + threadIdx.x) * 8;
  f32x4 a = *(const f32x4*)(in + i);
  f32x4 b = *(const f32x4*)(in + i + 4);
  u16x8 o;
#pragma unroll
  for (int j = 0; j < 4; ++j) { o[j] = f2bf(a[j]); o[j + 4] = f2bf(b[j]); }
  *(u16x8*)(out + i) = o;
}

// ---------------------------------------------------------------------------
// transpose+convert: in[R][C] f32 -> out[Cpad][R] bf16 (rows c>=C zero-filled)
// ---------------------------------------------------------------------------
__global__ __launch_bounds__(256) void transpose_conv(
    const float* __restrict__ in, unsigned short* __restrict__ out, int R,
    int C) {
  __shared__ __align__(16) unsigned short T[64][72];
  const int c0 = blockIdx.x * 64, r0 = blockIdx.y * 64;
  const int tid = threadIdx.x;
#pragma unroll
  for (int it = 0; it < 4; ++it) {
    int r = it * 16 + (tid >> 4);
    int c = (tid & 15) * 4;
    f32x4 v = {0.f, 0.f, 0.f, 0.f};
    if (c0 + c < C) v = *(const f32x4*)(in + (size_t)(r0 + r) * C + c0 + c);
#pragma unroll
    for (int j = 0; j < 4; ++j) T[c + j][r] = f2bf(v[j]);
  }
  __syncthreads();
  const int nr = tid >> 2, kc = (tid & 3) * 16;
  u16x8 a = *(const u16x8*)(&T[nr][kc]);
  u16x8 b = *(const u16x8*)(&T[nr][kc + 8]);
  unsigned short* o = out + (size_t)(c0 + nr) * R + r0 + kc;
  *(u16x8*)o = a;
  *(u16x8*)(o + 8) = b;
}

// ---------------------------------------------------------------------------
// Depthwise causal conv (4 taps) + bias + SiLU, bf16 in/out, 4 ch/thread
// ---------------------------------------------------------------------------
__global__ __launch_bounds__(256) void conv_kernel(
    const unsigned short* __restrict__ raw, const float* __restrict__ cw,
    const float* __restrict__ cb, unsigned short* __restrict__ xbc) {
  const int ch4 = blockIdx.x * 256 + threadIdx.x;
  if (ch4 >= 1088) return;
  const int ch = ch4 * 4;
  const int row = blockIdx.y;
  const int l = row & 2047;
  f32x4 acc = *(const f32x4*)(cb + ch);
  f32x4 w0 = *(const f32x4*)(cw + ch * 4);
  f32x4 w1 = *(const f32x4*)(cw + ch * 4 + 4);
  f32x4 w2 = *(const f32x4*)(cw + ch * 4 + 8);
  f32x4 w3 = *(const f32x4*)(cw + ch * 4 + 12);
#pragma unroll
  for (int k = 0; k < 4; ++k) {
    int ls = l - 3 + k;
    if (ls >= 0) {
      u16x4 v = *(const u16x4*)(raw + (size_t)(row - 3 + k) * 4352 + ch);
      acc[0] += w0[k] * bf2f(v[0]);
      acc[1] += w1[k] * bf2f(v[1]);
      acc[2] += w2[k] * bf2f(v[2]);
      acc[3] += w3[k] * bf2f(v[3]);
    }
  }
  u16x4 o;
#pragma unroll
  for (int j = 0; j < 4; ++j) {
    float s = acc[j] / (1.0f + __expf(-acc[j]));
    o[j] = f2bf(s);
  }
  *(u16x4*)(xbc + (size_t)row * 4352 + ch) = o;
}

// ---------------------------------------------------------------------------
// dt softplus (in place) + per-chunk cumsum of dt*(-exp(A_log))
// ---------------------------------------------------------------------------
__global__ __launch_bounds__(256) void dt_kernel(
    float* __restrict__ dtb, const float* __restrict__ dt_bias,
    const float* __restrict__ A_log, float* __restrict__ Acs) {
  __shared__ float s[256];
  const int blk = blockIdx.x;
  const int c = blk & 7, h = (blk >> 3) & 63, b = blk >> 9;
  const int t = threadIdx.x;
  const int row = b * 2048 + c * 256 + t;
  float xv = dtb[(size_t)row * 64 + h] + dt_bias[h];
  float dt = (xv > 20.0f) ? xv : log1pf(__expf(xv));
  dtb[(size_t)row * 64 + h] = dt;
  float a = dt * (-__expf(A_log[h]));
  s[t] = a;
  __syncthreads();
  for (int off = 1; off < 256; off <<= 1) {
    float v = (t >= off) ? s[t - off] : 0.0f;
    __syncthreads();
    s[t] += v;
    __syncthreads();
  }
  Acs[((size_t)((b * 64 + h) * 8 + c)) * 256 + t] = s[t];
}

// ---------------------------------------------------------------------------
// G[bc][i][j] = sum_n Cm[i][n]*Bm[j][n] (head-independent)
// ---------------------------------------------------------------------------
__global__ __launch_bounds__(256) void g_kernel(
    const unsigned short* __restrict__ xbc, float* __restrict__ G) {
  const int bc = blockIdx.y;
  const int i0 = (blockIdx.x >> 2) * 64, j0 = (blockIdx.x & 3) * 64;
  const int tid = threadIdx.x;
  const int lane = tid & 63, w = tid >> 6;
  const int l16 = lane & 15, lq = lane >> 4;
  const unsigned short* base = xbc + (size_t)bc * 256 * 4352;
  f32x4 acc[4] = {};
#pragma unroll
  for (int ks = 0; ks < 4; ++ks) {
    int nb = ks * 32 + lq * 8;
    u16x8 af = *(const u16x8*)(base + (size_t)(i0 + w * 16 + l16) * 4352 + 4224 + nb);
#pragma unroll
    for (int jf = 0; jf < 4; ++jf) {
      u16x8 bb = *(const u16x8*)(base + (size_t)(j0 + jf * 16 + l16) * 4352 + 4096 + nb);
      acc[jf] = mfma16(af, bb, acc[jf]);
    }
  }
  float* Gt = G + (size_t)bc * 65536;
#pragma unroll
  for (int jf = 0; jf < 4; ++jf)
#pragma unroll
    for (int r = 0; r < 4; ++r)
      Gt[(i0 + w * 16 + lq * 4 + r) * 256 + j0 + jf * 16 + l16] = acc[jf][r];
}

// ---------------------------------------------------------------------------
// Per-chunk states: states[p][n] (bf16) = sum_t Bm[t][n]*decay(t)*X[t][p]
// ---------------------------------------------------------------------------
__global__ __launch_bounds__(512) void ssd_states(
    const unsigned short* __restrict__ xbc, const float* __restrict__ dtb,
    const float* __restrict__ Acs, unsigned short* __restrict__ statesb) {
  __shared__ __align__(16) unsigned short Xt[64 * 264];
  __shared__ __align__(16) unsigned short BmT[128 * 72];
  __shared__ float As_s[256];
  const int h = blockIdx.x, c = blockIdx.y, b = blockIdx.z;
  const int tid = threadIdx.x;
  const int lane = tid & 63, w = tid >> 6;
  const int l16 = lane & 15, lq = lane >> 4;
  const int row0 = b * 2048 + c * 256;

  if (tid < 256) As_s[tid] = Acs[((size_t)((b * 64 + h) * 8 + c)) * 256 + tid];
#pragma unroll
  for (int it = 0; it < 2; ++it) {
    int pb = tid & 15;
    int tb = it * 32 + (tid >> 4);
    float rr[4][4];
#pragma unroll
    for (int i = 0; i < 4; ++i) {
      int row = row0 + tb * 4 + i;
      u16x4 v = *(const u16x4*)(xbc + (size_t)row * 4352 + h * 64 + pb * 4);
      float dtv = dtb[(size_t)row * 64 + h];
#pragma unroll
      for (int j = 0; j < 4; ++j) rr[i][j] = bf2f(v[j]) * dtv;
    }
#pragma unroll
    for (int j = 0; j < 4; ++j) {
      u16x4 hh = {f2bf(rr[0][j]), f2bf(rr[1][j]), f2bf(rr[2][j]), f2bf(rr[3][j])};
      *(u16x4*)(&Xt[(pb * 4 + j) * 264 + tb * 4]) = hh;
    }
  }
  __syncthreads();

  f32x4 accS[4] = {};
  const float Alast = As_s[255];
  for (int part = 0; part < 4; ++part) {
    if (part) __syncthreads();
    {
      int nb = tid & 31;
      int tb = tid >> 5;
      float rr[4][4];
#pragma unroll
      for (int i = 0; i < 4; ++i) {
        int t = part * 64 + tb * 4 + i;
        int row = row0 + t;
        float dec = __expf(Alast - As_s[t]);
        u16x4 v = *(const u16x4*)(xbc + (size_t)row * 4352 + 4096 + nb * 4);
#pragma unroll
        for (int j = 0; j < 4; ++j) rr[i][j] = bf2f(v[j]) * dec;
      }
#pragma unroll
      for (int j = 0; j < 4; ++j) {
        u16x4 hh = {f2bf(rr[0][j]), f2bf(rr[1][j]), f2bf(rr[2][j]), f2bf(rr[3][j])};
        *(u16x4*)(&BmT[(nb * 4 + j) * 72 + tb * 4]) = hh;
      }
    }
    __syncthreads();
#pragma unroll
    for (int ks = 0; ks < 2; ++ks) {
      int toff = ks * 32 + lq * 8;
      u16x8 af = *(const u16x8*)(&BmT[(w * 16 + l16) * 72 + toff]);
#pragma unroll
      for (int pf = 0; pf < 4; ++pf) {
        u16x8 bfr = *(const u16x8*)(&Xt[(pf * 16 + l16) * 264 + part * 64 + toff]);
        accS[pf] = mfma16(af, bfr, accS[pf]);
      }
    }
  }
  unsigned short* Sp = statesb + (size_t)((b * 8 + c) * 64 + h) * 8192;
#pragma unroll
  for (int pf = 0; pf < 4; ++pf) {
    u16x4 hh = {f2bf(accS[pf][0]), f2bf(accS[pf][1]), f2bf(accS[pf][2]),
                f2bf(accS[pf][3])};
    *(u16x4*)(&Sp[(pf * 16 + l16) * 128 + w * 16 + lq * 4]) = hh;
  }
}

// ---------------------------------------------------------------------------
// Sequential chunk scan -> prefix states (bf16, [p][n]); grid (h, b)
// ---------------------------------------------------------------------------
__global__ __launch_bounds__(256) void scan_states(
    const unsigned short* __restrict__ statesb, const float* __restrict__ Acs,
    unsigned short* __restrict__ prefix) {
  const int h = blockIdx.x, b = blockIdx.y;
  const int tid = threadIdx.x;
  const int p = tid >> 2, nq = (tid & 3) * 32;
  float S[32];
#pragma unroll
  for (int i = 0; i < 32; ++i) S[i] = 0.0f;
  for (int cc = 0; cc < 8; ++cc) {
    size_t base = (size_t)((b * 8 + cc) * 64 + h) * 8192 + p * 128 + nq;
#pragma unroll
    for (int j = 0; j < 4; ++j) {
      u16x8 hh;
#pragma unroll
      for (int k = 0; k < 8; ++k) hh[k] = f2bf(S[j * 8 + k]);
      *(u16x8*)(prefix + base + j * 8) = hh;
    }
    float eAl = __expf(Acs[((size_t)((b * 64 + h) * 8 + cc)) * 256 + 255]);
#pragma unroll
    for (int j = 0; j < 4; ++j) {
      u16x8 v = *(const u16x8*)(statesb + base + j * 8);
#pragma unroll
      for (int k = 0; k < 8; ++k) S[j * 8 + k] = eAl * S[j * 8 + k] + bf2f(v[k]);
    }
  }
}

// ---------------------------------------------------------------------------
// Fused Y: Y_diag (G.*L @ X) + Y_off (exp(Acs)*Cm @ P^T) + D*xh -> y bf16
// ---------------------------------------------------------------------------
__global__ __launch_bounds__(512) void ssd_main(
    const unsigned short* __restrict__ xbc, const float* __restrict__ dtb,
    const float* __restrict__ Acs, const float* __restrict__ G,
    const unsigned short* __restrict__ prefix, const float* __restrict__ Dv,
    unsigned short* __restrict__ y) {
  __shared__ __align__(16) unsigned short Xt[64 * 264];
  __shared__ float As_s[256];
  const int h = blockIdx.x, c = blockIdx.y, b = blockIdx.z;
  const int tid = threadIdx.x;
  const int lane = tid & 63, w = tid >> 6;
  const int l16 = lane & 15, lq = lane >> 4;
  const int row0 = b * 2048 + c * 256;

  if (tid < 256) As_s[tid] = Acs[((size_t)((b * 64 + h) * 8 + c)) * 256 + tid];
#pragma unroll
  for (int it = 0; it < 2; ++it) {
    int pb = tid & 15;
    int tb = it * 32 + (tid >> 4);
    float rr[4][4];
#pragma unroll
    for (int i = 0; i < 4; ++i) {
      int row = row0 + tb * 4 + i;
      u16x4 v = *(const u16x4*)(xbc + (size_t)row * 4352 + h * 64 + pb * 4);
      float dtv = dtb[(size_t)row * 64 + h];
#pragma unroll
      for (int j = 0; j < 4; ++j) rr[i][j] = bf2f(v[j]) * dtv;
    }
#pragma unroll
    for (int j = 0; j < 4; ++j) {
      u16x4 hh = {f2bf(rr[0][j]), f2bf(rr[1][j]), f2bf(rr[2][j]), f2bf(rr[3][j])};
      *(u16x4*)(&Xt[(pb * 4 + j) * 264 + tb * 4]) = hh;
    }
  }
  __syncthreads();

  f32x4 acc[2][4] = {};
  const float* Gt = G + (size_t)(b * 8 + c) * 65536;
  for (int ks = 0; ks < 8; ++ks) {
    const int tb = ks * 32 + lq * 8;
    u16x8 bfr[4];
#pragma unroll
    for (int pf = 0; pf < 4; ++pf)
      bfr[pf] = *(const u16x8*)(&Xt[(pf * 16 + l16) * 264 + tb]);
#pragma unroll
    for (int mf = 0; mf < 2; ++mf) {
      const int i = w * 32 + mf * 16 + l16;
      const float ai = As_s[i];
      const float* gp = Gt + i * 256 + tb;
      f32x4 g0 = *(const f32x4*)gp;
      f32x4 g1 = *(const f32x4*)(gp + 4);
      u16x8 af;
#pragma unroll
      for (int jj = 0; jj < 8; ++jj) {
        int j = tb + jj;
        float g = (jj < 4) ? g0[jj] : g1[jj - 4];
        float v = (i >= j) ? g * __expf(ai - As_s[j]) : 0.0f;
        af[jj] = f2bf(v);
      }
#pragma unroll
      for (int pf = 0; pf < 4; ++pf)
        acc[mf][pf] = mfma16(af, bfr[pf], acc[mf][pf]);
    }
  }
  const unsigned short* Pf = prefix + (size_t)((b * 8 + c) * 64 + h) * 8192;
  for (int ks = 0; ks < 4; ++ks) {
    const int nb = ks * 32 + lq * 8;
    u16x8 bfr[4];
#pragma unroll
    for (int pf = 0; pf < 4; ++pf)
      bfr[pf] = *(const u16x8*)(Pf + (size_t)(pf * 16 + l16) * 128 + nb);
#pragma unroll
    for (int mf = 0; mf < 2; ++mf) {
      const int i = w * 32 + mf * 16 + l16;
      const float eAi = __expf(As_s[i]);
      u16x8 cv = *(const u16x8*)(xbc + (size_t)(row0 + i) * 4352 + 4224 + nb);
      u16x8 af;
#pragma unroll
      for (int jj = 0; jj < 8; ++jj) af[jj] = f2bf(bf2f(cv[jj]) * eAi);
#pragma unroll
      for (int pf = 0; pf < 4; ++pf)
        acc[mf][pf] = mfma16(af, bfr[pf], acc[mf][pf]);
    }
  }
  const float Dh = Dv[h];
#pragma unroll
  for (int mf = 0; mf < 2; ++mf) {
#pragma unroll
    for (int r = 0; r < 4; ++r) {
      int t = w * 32 + mf * 16 + lq * 4 + r;
      size_t row = (size_t)(row0 + t);
#pragma unroll
      for (int pf = 0; pf < 4; ++pf) {
        int p = pf * 16 + l16;
        float xh = bf2f(xbc[row * 4352 + h * 64 + p]);
        y[row * 4096 + h * 64 + p] = f2bf(acc[mf][pf][r] + Dh * xh);
      }
    }
  }
}

// ---------------------------------------------------------------------------
// In-place: y = rmsnorm(y * silu(z)) * norm_w  (bf16)
// ---------------------------------------------------------------------------
__global__ __launch_bounds__(256) void norm_kernel(
    unsigned short* __restrict__ y, const unsigned short* __restrict__ zbf,
    const float* __restrict__ nw) {
  const int row = blockIdx.x, tid = threadIdx.x;
  unsigned short* yr = y + (size_t)row * 4096;
  const unsigned short* zr = zbf + (size_t)row * 4096;
  float vals[16];
  float ss = 0.0f;
#pragma unroll
  for (int i = 0; i < 2; ++i) {
    int cb = i * 2048 + tid * 8;
    u16x8 yv = *(const u16x8*)(yr + cb);
    u16x8 zv = *(const u16x8*)(zr + cb);
#pragma unroll
    for (int j = 0; j < 8; ++j) {
      float z = bf2f(zv[j]);
      float g = bf2f(yv[j]) * (z / (1.0f + __expf(-z)));
      vals[i * 8 + j] = g;
      ss += g * g;
    }
  }
#pragma unroll
  for (int off = 32; off > 0; off >>= 1) ss += __shfl_xor(ss, off, 64);
  __shared__ float red[4];
  if ((tid & 63) == 0) red[tid >> 6] = ss;
  __syncthreads();
  float tot = red[0] + red[1] + red[2] + red[3];
  float rr = rsqrtf(tot * (1.0f / 4096.0f) + 1e-5f);
#pragma unroll
  for (int i = 0; i < 2; ++i) {
    int cb = i * 2048 + tid * 8;
    f32x4 w0 = *(const f32x4*)(nw + cb);
    f32x4 w1 = *(const f32x4*)(nw + cb + 4);
    u16x8 o;
#pragma unroll
    for (int j = 0; j < 8; ++j) {
      float wv = (j < 4) ? w0[j] : w1[j - 4];
      o[j] = f2bf(vals[i * 8 + j] * rr * wv);
    }
    *(u16x8*)(yr + cb) = o;
  }
}

// ---------------------------------------------------------------------------
extern "C" void kernel_launch(void* const* d_in, const int* in_sizes, int n_in,
                              void* d_out, int out_size, void* d_ws,
                              size_t ws_size, hipStream_t stream) {
  const float* x = (const float*)d_in[0];
  const float* w_in = (const float*)d_in[1];
  const float* conv_w = (const float*)d_in[2];
  const float* conv_b = (const float*)d_in[3];
  const float* dt_bias = (const float*)d_in[4];
  const float* A_log = (const float*)d_in[5];
  const float* Dvec = (const float*)d_in[6];
  const float* norm_w = (const float*)d_in[7];
  const float* w_out = (const float*)d_in[8];
  float* out = (float*)d_out;

  char* w = (char*)d_ws;
  unsigned short* zbf = (unsigned short*)(w + 0);            // 33,554,432
  unsigned short* xbc = (unsigned short*)(w + 33554432);     // 35,651,584
  unsigned short* xbcraw = (unsigned short*)(w + 69206016);  // 35,651,584 (→prefix)
  float* dtb = (float*)(w + 104857600);                      // 1,048,576
  float* Acs = (float*)(w + 105906176);                      // 1,048,576
  float* G = (float*)(w + 106954752);                        // 4,194,304
  unsigned short* statesb = (unsigned short*)(w + 111149056);// 16,777,216
  unsigned short* y = (unsigned short*)(w + 127926272);      // 33,554,432
  // aliases (lifetimes disjoint, single stream):
  unsigned short* xbf = (unsigned short*)(w + 111149056);    // = statesb region
  unsigned short* w_inT = (unsigned short*)(w + 33554432);   // = xbc region (8704x2048 = 35,651,584 B)
  unsigned short* w_outT = (unsigned short*)(w + 33554432);  // = xbc region (2048x4096)
  unsigned short* prefix = xbcraw;

  convert_bf16<<<dim3(4096), 256, 0, stream>>>(x, xbf);
  transpose_conv<<<dim3(136, 32), 256, 0, stream>>>(w_in, w_inT, 2048, 8512);
  gemm_p<256, 256, 0><<<dim3(34, 16), 512, 0, stream>>>(
      xbf, w_inT, 2048, zbf, xbcraw, dtb, nullptr, nullptr);
  conv_kernel<<<dim3(5, 4096), 256, 0, stream>>>(xbcraw, conv_w, conv_b, xbc);
  dt_kernel<<<dim3(1024), 256, 0, stream>>>(dtb, dt_bias, A_log, Acs);
  g_kernel<<<dim3(16, 16), 256, 0, stream>>>(xbc, G);
  ssd_states<<<dim3(64, 8, 2), 512, 0, stream>>>(xbc, dtb, Acs, statesb);
  scan_states<<<dim3(64, 2), 256, 0, stream>>>(statesb, Acs, prefix);
  ssd_main<<<dim3(64, 8, 2), 512, 0, stream>>>(xbc, dtb, Acs, G, prefix, Dvec, y);
  transpose_conv<<<dim3(32, 64), 256, 0, stream>>>(w_out, w_outT, 4096, 2048);
  norm_kernel<<<dim3(4096), 256, 0, stream>>>(y, zbf, norm_w);
  gemm_p<128, 256, 1><<<dim3(8, 32), 512, 0, stream>>>(
      y, w_outT, 4096, nullptr, nullptr, nullptr, out, x);
}

// Round 5
// 503.394 us; speedup vs baseline: 1.4654x; 1.0987x over previous
//
#include <hip/hip_runtime.h>
#include <math.h>

#define DEV __device__ __forceinline__

typedef __attribute__((ext_vector_type(4))) float f32x4;
typedef __attribute__((ext_vector_type(4))) unsigned short u16x4;
typedef __attribute__((ext_vector_type(8))) unsigned short u16x8;
typedef __attribute__((ext_vector_type(8))) __bf16 bfv8;

DEV unsigned short f2bf(float f) {
  unsigned u = __builtin_bit_cast(unsigned, f);
  u = (u + 0x7FFFu + ((u >> 16) & 1u)) >> 16;
  return (unsigned short)u;
}
DEV float bf2f(unsigned short h) {
  unsigned u = ((unsigned)h) << 16;
  return __builtin_bit_cast(float, u);
}

DEV f32x4 mfma16(u16x8 a, u16x8 b, f32x4 c) {
  return __builtin_amdgcn_mfma_f32_16x16x32_bf16(
      __builtin_bit_cast(bfv8, a), __builtin_bit_cast(bfv8, b), c, 0, 0, 0);
}

DEV void gload_lds16(const unsigned short* g, unsigned short* s) {
  __builtin_amdgcn_global_load_lds(
      (const __attribute__((address_space(1))) void*)g,
      (__attribute__((address_space(3))) void*)s, 16, 0, 0);
}

template <int N>
DEV void vmcnt_wait() {
  if constexpr (N == 0) asm volatile("s_waitcnt vmcnt(0)" ::: "memory");
  else if constexpr (N == 2) asm volatile("s_waitcnt vmcnt(2)" ::: "memory");
  else if constexpr (N == 3) asm volatile("s_waitcnt vmcnt(3)" ::: "memory");
  else if constexpr (N == 4) asm volatile("s_waitcnt vmcnt(4)" ::: "memory");
  else if constexpr (N == 6) asm volatile("s_waitcnt vmcnt(6)" ::: "memory");
  else if constexpr (N == 8) asm volatile("s_waitcnt vmcnt(8)" ::: "memory");
}

// ---------------------------------------------------------------------------
// Fine-phased pipelined bf16 GEMM: C[M,N] = A[M,K] @ Bt[N,K]^T.
// BK=32, 3-buffer ring, 2 phases/K-tile, 16 MFMA + 1 half-stage per phase,
// counted vmcnt once per K-tile (never 0 in steady state).
// 512 thr / 8 waves (2M x 4N). Both-sides XOR chunk swizzle (verified: 0
// bank conflicts). MODE 0: in_proj routing epilogue; MODE 1: +resid -> f32.
// ---------------------------------------------------------------------------
template <int BM, int BN, int MODE>
__global__ __launch_bounds__(512, 2) void gemm_p(
    const unsigned short* __restrict__ A, const unsigned short* __restrict__ Bt,
    int K, unsigned short* __restrict__ o_z, unsigned short* __restrict__ o_xbc,
    float* __restrict__ o_dt, float* __restrict__ o_c,
    const float* __restrict__ resid) {
  constexpr int LA = BM / 128, LB = BN / 128, L = LA + LB;
  constexpr int MF = BM / 32, NF = BN / 64, MH = MF / 2;
  __shared__ __align__(16) unsigned short As[3][BM * 32];
  __shared__ __align__(16) unsigned short Bs[3][BN * 32];
  const int tid = threadIdx.x;
  const int lane = tid & 63, w = tid >> 6;
  const int l16 = lane & 15, lq = lane >> 4;
  const int wr = w >> 2, wc = w & 3;
  const int nwg = gridDim.x * gridDim.y;
  int lin = blockIdx.y * gridDim.x + blockIdx.x;
  lin = (lin & 7) * (nwg >> 3) + (lin >> 3);
  const int m0 = (lin / gridDim.x) * BM, n0 = (lin % gridDim.x) * BN;
  const int lrow = lane >> 2;                     // staged row within 16
  const int gq = (lane & 3) ^ ((lrow >> 1) & 3);  // pre-swizzled src chunk
  const int cq = lq ^ ((l16 >> 1) & 3);           // swizzled read chunk

  const unsigned short* Ag = A + (size_t)(m0 + lrow) * K + gq * 8;
  const unsigned short* Bg = Bt + (size_t)(n0 + lrow) * K + gq * 8;

  f32x4 acc[MF][NF] = {};
  u16x8 bf[NF];

  auto stageA = [&](int bi, int kt) {
#pragma unroll
    for (int i = 0; i < LA; ++i) {
      const int rb = (w + i * 8) * 16;
      gload_lds16(Ag + (size_t)rb * K + kt * 32, &As[bi][rb * 32]);
    }
  };
  auto stageB = [&](int bi, int kt) {
#pragma unroll
    for (int i = 0; i < LB; ++i) {
      const int rb = (w + i * 8) * 16;
      gload_lds16(Bg + (size_t)rb * K + kt * 32, &Bs[bi][rb * 32]);
    }
  };

  const int nt = K / 32;
  stageA(0, 0); stageB(0, 0);
  stageA(1, 1); stageB(1, 1);
  vmcnt_wait<L>();
  __builtin_amdgcn_s_barrier();

  for (int k = 0; k < nt; ++k) {
    const int cb = k % 3;
    const bool st = (k + 2) < nt;
    const int pb = st ? (k + 2) % 3 : 0;
    // ---- phase 0: M-frags 0..MH-1, stage A-half of tile k+2
    u16x8 af[MH];
#pragma unroll
    for (int mf = 0; mf < MH; ++mf)
      af[mf] = *(const u16x8*)(&As[cb][(wr * (BM / 2) + mf * 16 + l16) * 32 + cq * 8]);
#pragma unroll
    for (int nf = 0; nf < NF; ++nf)
      bf[nf] = *(const u16x8*)(&Bs[cb][(wc * (BN / 4) + nf * 16 + l16) * 32 + cq * 8]);
    if (st) stageA(pb, k + 2);
    asm volatile("" ::: "memory");
    __builtin_amdgcn_s_barrier();
    __builtin_amdgcn_s_setprio(1);
#pragma unroll
    for (int mf = 0; mf < MH; ++mf)
#pragma unroll
      for (int nf = 0; nf < NF; ++nf)
        acc[mf][nf] = mfma16(af[mf], bf[nf], acc[mf][nf]);
    __builtin_amdgcn_s_setprio(0);
    asm volatile("" ::: "memory");
    __builtin_amdgcn_s_barrier();
    // ---- phase 1: M-frags MH..MF-1, stage B-half of tile k+2
#pragma unroll
    for (int mf = 0; mf < MH; ++mf)
      af[mf] = *(const u16x8*)(&As[cb][(wr * (BM / 2) + (MH + mf) * 16 + l16) * 32 + cq * 8]);
    if (st) stageB(pb, k + 2);
    asm volatile("" ::: "memory");
    __builtin_amdgcn_s_barrier();
    __builtin_amdgcn_s_setprio(1);
#pragma unroll
    for (int mf = 0; mf < MH; ++mf)
#pragma unroll
      for (int nf = 0; nf < NF; ++nf)
        acc[MH + mf][nf] = mfma16(af[mf], bf[nf], acc[MH + mf][nf]);
    __builtin_amdgcn_s_setprio(0);
    if (k + 1 < nt) {
      if (st) vmcnt_wait<L>();
      else vmcnt_wait<0>();
    }
    asm volatile("" ::: "memory");
    __builtin_amdgcn_s_barrier();
  }

#pragma unroll
  for (int mf = 0; mf < MF; ++mf) {
#pragma unroll
    for (int nf = 0; nf < NF; ++nf) {
      const int col = n0 + wc * (BN / 4) + nf * 16 + l16;
#pragma unroll
      for (int r = 0; r < 4; ++r) {
        const int row = m0 + wr * (BM / 2) + mf * 16 + lq * 4 + r;
        float v = acc[mf][nf][r];
        if constexpr (MODE == 0) {
          if (col < 4096) o_z[(size_t)row * 4096 + col] = f2bf(v);
          else if (col < 8448) o_xbc[(size_t)row * 4352 + (col - 4096)] = f2bf(v);
          else if (col < 8512) o_dt[(size_t)row * 64 + (col - 8448)] = v;
        } else {
          size_t idx = (size_t)row * 2048 + col;
          o_c[idx] = v + resid[idx];
        }
      }
    }
  }
}

// ---------------------------------------------------------------------------
// x f32 -> bf16 (elementwise, 8/thread)
// ---------------------------------------------------------------------------
__global__ __launch_bounds__(256) void convert_bf16(
    const float* __restrict__ in, unsigned short* __restrict__ out) {
  const size_t i = ((size_t)blockIdx.x * 256 + threadIdx.x) * 8;
  f32x4 a = *(const f32x4*)(in + i);
  f32x4 b = *(const f32x4*)(in + i + 4);
  u16x8 o;
#pragma unroll
  for (int j = 0; j < 4; ++j) { o[j] = f2bf(a[j]); o[j + 4] = f2bf(b[j]); }
  *(u16x8*)(out + i) = o;
}

// ---------------------------------------------------------------------------
// transpose+convert: in[R][C] f32 -> out[Cpad][R] bf16 (rows c>=C zero-filled)
// ---------------------------------------------------------------------------
__global__ __launch_bounds__(256) void transpose_conv(
    const float* __restrict__ in, unsigned short* __restrict__ out, int R,
    int C) {
  __shared__ __align__(16) unsigned short T[64][72];
  const int c0 = blockIdx.x * 64, r0 = blockIdx.y * 64;
  const int tid = threadIdx.x;
#pragma unroll
  for (int it = 0; it < 4; ++it) {
    int r = it * 16 + (tid >> 4);
    int c = (tid & 15) * 4;
    f32x4 v = {0.f, 0.f, 0.f, 0.f};
    if (c0 + c < C) v = *(const f32x4*)(in + (size_t)(r0 + r) * C + c0 + c);
#pragma unroll
    for (int j = 0; j < 4; ++j) T[c + j][r] = f2bf(v[j]);
  }
  __syncthreads();
  const int nr = tid >> 2, kc = (tid & 3) * 16;
  u16x8 a = *(const u16x8*)(&T[nr][kc]);
  u16x8 b = *(const u16x8*)(&T[nr][kc + 8]);
  unsigned short* o = out + (size_t)(c0 + nr) * R + r0 + kc;
  *(u16x8*)o = a;
  *(u16x8*)(o + 8) = b;
}

// ---------------------------------------------------------------------------
// Depthwise causal conv (4 taps) + bias + SiLU, bf16 in/out, 4 ch/thread
// ---------------------------------------------------------------------------
__global__ __launch_bounds__(256) void conv_kernel(
    const unsigned short* __restrict__ raw, const float* __restrict__ cw,
    const float* __restrict__ cb, unsigned short* __restrict__ xbc) {
  const int ch4 = blockIdx.x * 256 + threadIdx.x;
  if (ch4 >= 1088) return;
  const int ch = ch4 * 4;
  const int row = blockIdx.y;
  const int l = row & 2047;
  f32x4 acc = *(const f32x4*)(cb + ch);
  f32x4 w0 = *(const f32x4*)(cw + ch * 4);
  f32x4 w1 = *(const f32x4*)(cw + ch * 4 + 4);
  f32x4 w2 = *(const f32x4*)(cw + ch * 4 + 8);
  f32x4 w3 = *(const f32x4*)(cw + ch * 4 + 12);
#pragma unroll
  for (int k = 0; k < 4; ++k) {
    int ls = l - 3 + k;
    if (ls >= 0) {
      u16x4 v = *(const u16x4*)(raw + (size_t)(row - 3 + k) * 4352 + ch);
      acc[0] += w0[k] * bf2f(v[0]);
      acc[1] += w1[k] * bf2f(v[1]);
      acc[2] += w2[k] * bf2f(v[2]);
      acc[3] += w3[k] * bf2f(v[3]);
    }
  }
  u16x4 o;
#pragma unroll
  for (int j = 0; j < 4; ++j) {
    float s = acc[j] / (1.0f + __expf(-acc[j]));
    o[j] = f2bf(s);
  }
  *(u16x4*)(xbc + (size_t)row * 4352 + ch) = o;
}

// ---------------------------------------------------------------------------
// dt softplus (in place) + per-chunk cumsum of dt*(-exp(A_log))
// ---------------------------------------------------------------------------
__global__ __launch_bounds__(256) void dt_kernel(
    float* __restrict__ dtb, const float* __restrict__ dt_bias,
    const float* __restrict__ A_log, float* __restrict__ Acs) {
  __shared__ float s[256];
  const int blk = blockIdx.x;
  const int c = blk & 7, h = (blk >> 3) & 63, b = blk >> 9;
  const int t = threadIdx.x;
  const int row = b * 2048 + c * 256 + t;
  float xv = dtb[(size_t)row * 64 + h] + dt_bias[h];
  float dt = (xv > 20.0f) ? xv : log1pf(__expf(xv));
  dtb[(size_t)row * 64 + h] = dt;
  float a = dt * (-__expf(A_log[h]));
  s[t] = a;
  __syncthreads();
  for (int off = 1; off < 256; off <<= 1) {
    float v = (t >= off) ? s[t - off] : 0.0f;
    __syncthreads();
    s[t] += v;
    __syncthreads();
  }
  Acs[((size_t)((b * 64 + h) * 8 + c)) * 256 + t] = s[t];
}

// ---------------------------------------------------------------------------
// G[bc][i][j] = sum_n Cm[i][n]*Bm[j][n] (head-independent)
// ---------------------------------------------------------------------------
__global__ __launch_bounds__(256) void g_kernel(
    const unsigned short* __restrict__ xbc, float* __restrict__ G) {
  const int bc = blockIdx.y;
  const int i0 = (blockIdx.x >> 2) * 64, j0 = (blockIdx.x & 3) * 64;
  const int tid = threadIdx.x;
  const int lane = tid & 63, w = tid >> 6;
  const int l16 = lane & 15, lq = lane >> 4;
  const unsigned short* base = xbc + (size_t)bc * 256 * 4352;
  f32x4 acc[4] = {};
#pragma unroll
  for (int ks = 0; ks < 4; ++ks) {
    int nb = ks * 32 + lq * 8;
    u16x8 af = *(const u16x8*)(base + (size_t)(i0 + w * 16 + l16) * 4352 + 4224 + nb);
#pragma unroll
    for (int jf = 0; jf < 4; ++jf) {
      u16x8 bb = *(const u16x8*)(base + (size_t)(j0 + jf * 16 + l16) * 4352 + 4096 + nb);
      acc[jf] = mfma16(af, bb, acc[jf]);
    }
  }
  float* Gt = G + (size_t)bc * 65536;
#pragma unroll
  for (int jf = 0; jf < 4; ++jf)
#pragma unroll
    for (int r = 0; r < 4; ++r)
      Gt[(i0 + w * 16 + lq * 4 + r) * 256 + j0 + jf * 16 + l16] = acc[jf][r];
}

// ---------------------------------------------------------------------------
// Per-chunk states: states[p][n] (bf16) = sum_t Bm[t][n]*decay(t)*X[t][p]
// ---------------------------------------------------------------------------
__global__ __launch_bounds__(512) void ssd_states(
    const unsigned short* __restrict__ xbc, const float* __restrict__ dtb,
    const float* __restrict__ Acs, unsigned short* __restrict__ statesb) {
  __shared__ __align__(16) unsigned short Xt[64 * 264];
  __shared__ __align__(16) unsigned short BmT[128 * 72];
  __shared__ float As_s[256];
  const int h = blockIdx.x, c = blockIdx.y, b = blockIdx.z;
  const int tid = threadIdx.x;
  const int lane = tid & 63, w = tid >> 6;
  const int l16 = lane & 15, lq = lane >> 4;
  const int row0 = b * 2048 + c * 256;

  if (tid < 256) As_s[tid] = Acs[((size_t)((b * 64 + h) * 8 + c)) * 256 + tid];
#pragma unroll
  for (int it = 0; it < 2; ++it) {
    int pb = tid & 15;
    int tb = it * 32 + (tid >> 4);
    float rr[4][4];
#pragma unroll
    for (int i = 0; i < 4; ++i) {
      int row = row0 + tb * 4 + i;
      u16x4 v = *(const u16x4*)(xbc + (size_t)row * 4352 + h * 64 + pb * 4);
      float dtv = dtb[(size_t)row * 64 + h];
#pragma unroll
      for (int j = 0; j < 4; ++j) rr[i][j] = bf2f(v[j]) * dtv;
    }
#pragma unroll
    for (int j = 0; j < 4; ++j) {
      u16x4 hh = {f2bf(rr[0][j]), f2bf(rr[1][j]), f2bf(rr[2][j]), f2bf(rr[3][j])};
      *(u16x4*)(&Xt[(pb * 4 + j) * 264 + tb * 4]) = hh;
    }
  }
  __syncthreads();

  f32x4 accS[4] = {};
  const float Alast = As_s[255];
  for (int part = 0; part < 4; ++part) {
    if (part) __syncthreads();
    {
      int nb = tid & 31;
      int tb = tid >> 5;
      float rr[4][4];
#pragma unroll
      for (int i = 0; i < 4; ++i) {
        int t = part * 64 + tb * 4 + i;
        int row = row0 + t;
        float dec = __expf(Alast - As_s[t]);
        u16x4 v = *(const u16x4*)(xbc + (size_t)row * 4352 + 4096 + nb * 4);
#pragma unroll
        for (int j = 0; j < 4; ++j) rr[i][j] = bf2f(v[j]) * dec;
      }
#pragma unroll
      for (int j = 0; j < 4; ++j) {
        u16x4 hh = {f2bf(rr[0][j]), f2bf(rr[1][j]), f2bf(rr[2][j]), f2bf(rr[3][j])};
        *(u16x4*)(&BmT[(nb * 4 + j) * 72 + tb * 4]) = hh;
      }
    }
    __syncthreads();
#pragma unroll
    for (int ks = 0; ks < 2; ++ks) {
      int toff = ks * 32 + lq * 8;
      u16x8 af = *(const u16x8*)(&BmT[(w * 16 + l16) * 72 + toff]);
#pragma unroll
      for (int pf = 0; pf < 4; ++pf) {
        u16x8 bfr = *(const u16x8*)(&Xt[(pf * 16 + l16) * 264 + part * 64 + toff]);
        accS[pf] = mfma16(af, bfr, accS[pf]);
      }
    }
  }
  unsigned short* Sp = statesb + (size_t)((b * 8 + c) * 64 + h) * 8192;
#pragma unroll
  for (int pf = 0; pf < 4; ++pf) {
    u16x4 hh = {f2bf(accS[pf][0]), f2bf(accS[pf][1]), f2bf(accS[pf][2]),
                f2bf(accS[pf][3])};
    *(u16x4*)(&Sp[(pf * 16 + l16) * 128 + w * 16 + lq * 4]) = hh;
  }
}

// ---------------------------------------------------------------------------
// Sequential chunk scan -> prefix states (bf16, [p][n]); grid (h, b)
// ---------------------------------------------------------------------------
__global__ __launch_bounds__(256) void scan_states(
    const unsigned short* __restrict__ statesb, const float* __restrict__ Acs,
    unsigned short* __restrict__ prefix) {
  const int h = blockIdx.x, b = blockIdx.y;
  const int tid = threadIdx.x;
  const int p = tid >> 2, nq = (tid & 3) * 32;
  float S[32];
#pragma unroll
  for (int i = 0; i < 32; ++i) S[i] = 0.0f;
  for (int cc = 0; cc < 8; ++cc) {
    size_t base = (size_t)((b * 8 + cc) * 64 + h) * 8192 + p * 128 + nq;
#pragma unroll
    for (int j = 0; j < 4; ++j) {
      u16x8 hh;
#pragma unroll
      for (int k = 0; k < 8; ++k) hh[k] = f2bf(S[j * 8 + k]);
      *(u16x8*)(prefix + base + j * 8) = hh;
    }
    float eAl = __expf(Acs[((size_t)((b * 64 + h) * 8 + cc)) * 256 + 255]);
#pragma unroll
    for (int j = 0; j < 4; ++j) {
      u16x8 v = *(const u16x8*)(statesb + base + j * 8);
#pragma unroll
      for (int k = 0; k < 8; ++k) S[j * 8 + k] = eAl * S[j * 8 + k] + bf2f(v[k]);
    }
  }
}

// ---------------------------------------------------------------------------
// Fused Y: Y_diag (G.*L @ X) + Y_off (exp(Acs)*Cm @ P^T) + D*xh -> y bf16
// ---------------------------------------------------------------------------
__global__ __launch_bounds__(512) void ssd_main(
    const unsigned short* __restrict__ xbc, const float* __restrict__ dtb,
    const float* __restrict__ Acs, const float* __restrict__ G,
    const unsigned short* __restrict__ prefix, const float* __restrict__ Dv,
    unsigned short* __restrict__ y) {
  __shared__ __align__(16) unsigned short Xt[64 * 264];
  __shared__ float As_s[256];
  const int h = blockIdx.x, c = blockIdx.y, b = blockIdx.z;
  const int tid = threadIdx.x;
  const int lane = tid & 63, w = tid >> 6;
  const int l16 = lane & 15, lq = lane >> 4;
  const int row0 = b * 2048 + c * 256;

  if (tid < 256) As_s[tid] = Acs[((size_t)((b * 64 + h) * 8 + c)) * 256 + tid];
#pragma unroll
  for (int it = 0; it < 2; ++it) {
    int pb = tid & 15;
    int tb = it * 32 + (tid >> 4);
    float rr[4][4];
#pragma unroll
    for (int i = 0; i < 4; ++i) {
      int row = row0 + tb * 4 + i;
      u16x4 v = *(const u16x4*)(xbc + (size_t)row * 4352 + h * 64 + pb * 4);
      float dtv = dtb[(size_t)row * 64 + h];
#pragma unroll
      for (int j = 0; j < 4; ++j) rr[i][j] = bf2f(v[j]) * dtv;
    }
#pragma unroll
    for (int j = 0; j < 4; ++j) {
      u16x4 hh = {f2bf(rr[0][j]), f2bf(rr[1][j]), f2bf(rr[2][j]), f2bf(rr[3][j])};
      *(u16x4*)(&Xt[(pb * 4 + j) * 264 + tb * 4]) = hh;
    }
  }
  __syncthreads();

  f32x4 acc[2][4] = {};
  const float* Gt = G + (size_t)(b * 8 + c) * 65536;
  for (int ks = 0; ks < 8; ++ks) {
    const int tb = ks * 32 + lq * 8;
    u16x8 bfr[4];
#pragma unroll
    for (int pf = 0; pf < 4; ++pf)
      bfr[pf] = *(const u16x8*)(&Xt[(pf * 16 + l16) * 264 + tb]);
#pragma unroll
    for (int mf = 0; mf < 2; ++mf) {
      const int i = w * 32 + mf * 16 + l16;
      const float ai = As_s[i];
      const float* gp = Gt + i * 256 + tb;
      f32x4 g0 = *(const f32x4*)gp;
      f32x4 g1 = *(const f32x4*)(gp + 4);
      u16x8 af;
#pragma unroll
      for (int jj = 0; jj < 8; ++jj) {
        int j = tb + jj;
        float g = (jj < 4) ? g0[jj] : g1[jj - 4];
        float v = (i >= j) ? g * __expf(ai - As_s[j]) : 0.0f;
        af[jj] = f2bf(v);
      }
#pragma unroll
      for (int pf = 0; pf < 4; ++pf)
        acc[mf][pf] = mfma16(af, bfr[pf], acc[mf][pf]);
    }
  }
  const unsigned short* Pf = prefix + (size_t)((b * 8 + c) * 64 + h) * 8192;
  for (int ks = 0; ks < 4; ++ks) {
    const int nb = ks * 32 + lq * 8;
    u16x8 bfr[4];
#pragma unroll
    for (int pf = 0; pf < 4; ++pf)
      bfr[pf] = *(const u16x8*)(Pf + (size_t)(pf * 16 + l16) * 128 + nb);
#pragma unroll
    for (int mf = 0; mf < 2; ++mf) {
      const int i = w * 32 + mf * 16 + l16;
      const float eAi = __expf(As_s[i]);
      u16x8 cv = *(const u16x8*)(xbc + (size_t)(row0 + i) * 4352 + 4224 + nb);
      u16x8 af;
#pragma unroll
      for (int jj = 0; jj < 8; ++jj) af[jj] = f2bf(bf2f(cv[jj]) * eAi);
#pragma unroll
      for (int pf = 0; pf < 4; ++pf)
        acc[mf][pf] = mfma16(af, bfr[pf], acc[mf][pf]);
    }
  }
  const float Dh = Dv[h];
#pragma unroll
  for (int mf = 0; mf < 2; ++mf) {
#pragma unroll
    for (int r = 0; r < 4; ++r) {
      int t = w * 32 + mf * 16 + lq * 4 + r;
      size_t row = (size_t)(row0 + t);
#pragma unroll
      for (int pf = 0; pf < 4; ++pf) {
        int p = pf * 16 + l16;
        float xh = bf2f(xbc[row * 4352 + h * 64 + p]);
        y[row * 4096 + h * 64 + p] = f2bf(acc[mf][pf][r] + Dh * xh);
      }
    }
  }
}

// ---------------------------------------------------------------------------
// In-place: y = rmsnorm(y * silu(z)) * norm_w  (bf16)
// ---------------------------------------------------------------------------
__global__ __launch_bounds__(256) void norm_kernel(
    unsigned short* __restrict__ y, const unsigned short* __restrict__ zbf,
    const float* __restrict__ nw) {
  const int row = blockIdx.x, tid = threadIdx.x;
  unsigned short* yr = y + (size_t)row * 4096;
  const unsigned short* zr = zbf + (size_t)row * 4096;
  float vals[16];
  float ss = 0.0f;
#pragma unroll
  for (int i = 0; i < 2; ++i) {
    int cb = i * 2048 + tid * 8;
    u16x8 yv = *(const u16x8*)(yr + cb);
    u16x8 zv = *(const u16x8*)(zr + cb);
#pragma unroll
    for (int j = 0; j < 8; ++j) {
      float z = bf2f(zv[j]);
      float g = bf2f(yv[j]) * (z / (1.0f + __expf(-z)));
      vals[i * 8 + j] = g;
      ss += g * g;
    }
  }
#pragma unroll
  for (int off = 32; off > 0; off >>= 1) ss += __shfl_xor(ss, off, 64);
  __shared__ float red[4];
  if ((tid & 63) == 0) red[tid >> 6] = ss;
  __syncthreads();
  float tot = red[0] + red[1] + red[2] + red[3];
  float rr = rsqrtf(tot * (1.0f / 4096.0f) + 1e-5f);
#pragma unroll
  for (int i = 0; i < 2; ++i) {
    int cb = i * 2048 + tid * 8;
    f32x4 w0 = *(const f32x4*)(nw + cb);
    f32x4 w1 = *(const f32x4*)(nw + cb + 4);
    u16x8 o;
#pragma unroll
    for (int j = 0; j < 8; ++j) {
      float wv = (j < 4) ? w0[j] : w1[j - 4];
      o[j] = f2bf(vals[i * 8 + j] * rr * wv);
    }
    *(u16x8*)(yr + cb) = o;
  }
}

// ---------------------------------------------------------------------------
extern "C" void kernel_launch(void* const* d_in, const int* in_sizes, int n_in,
                              void* d_out, int out_size, void* d_ws,
                              size_t ws_size, hipStream_t stream) {
  const float* x = (const float*)d_in[0];
  const float* w_in = (const float*)d_in[1];
  const float* conv_w = (const float*)d_in[2];
  const float* conv_b = (const float*)d_in[3];
  const float* dt_bias = (const float*)d_in[4];
  const float* A_log = (const float*)d_in[5];
  const float* Dvec = (const float*)d_in[6];
  const float* norm_w = (const float*)d_in[7];
  const float* w_out = (const float*)d_in[8];
  float* out = (float*)d_out;

  char* w = (char*)d_ws;
  unsigned short* zbf = (unsigned short*)(w + 0);            // 33,554,432
  unsigned short* xbc = (unsigned short*)(w + 33554432);     // 35,651,584
  unsigned short* xbcraw = (unsigned short*)(w + 69206016);  // 35,651,584 (→prefix)
  float* dtb = (float*)(w + 104857600);                      // 1,048,576
  float* Acs = (float*)(w + 105906176);                      // 1,048,576
  float* G = (float*)(w + 106954752);                        // 4,194,304
  unsigned short* statesb = (unsigned short*)(w + 111149056);// 16,777,216
  unsigned short* y = (unsigned short*)(w + 127926272);      // 33,554,432
  // aliases (lifetimes disjoint, single stream):
  unsigned short* xbf = (unsigned short*)(w + 111149056);    // = statesb region
  unsigned short* w_inT = (unsigned short*)(w + 33554432);   // = xbc region (8704x2048)
  unsigned short* w_outT = (unsigned short*)(w + 33554432);  // = xbc region (2048x4096)
  unsigned short* prefix = xbcraw;

  convert_bf16<<<dim3(4096), 256, 0, stream>>>(x, xbf);
  transpose_conv<<<dim3(136, 32), 256, 0, stream>>>(w_in, w_inT, 2048, 8512);
  gemm_p<256, 256, 0><<<dim3(34, 16), 512, 0, stream>>>(
      xbf, w_inT, 2048, zbf, xbcraw, dtb, nullptr, nullptr);
  conv_kernel<<<dim3(5, 4096), 256, 0, stream>>>(xbcraw, conv_w, conv_b, xbc);
  dt_kernel<<<dim3(1024), 256, 0, stream>>>(dtb, dt_bias, A_log, Acs);
  g_kernel<<<dim3(16, 16), 256, 0, stream>>>(xbc, G);
  ssd_states<<<dim3(64, 8, 2), 512, 0, stream>>>(xbc, dtb, Acs, statesb);
  scan_states<<<dim3(64, 2), 256, 0, stream>>>(statesb, Acs, prefix);
  ssd_main<<<dim3(64, 8, 2), 512, 0, stream>>>(xbc, dtb, Acs, G, prefix, Dvec, y);
  transpose_conv<<<dim3(32, 64), 256, 0, stream>>>(w_out, w_outT, 4096, 2048);
  norm_kernel<<<dim3(4096), 256, 0, stream>>>(y, zbf, norm_w);
  gemm_p<128, 128, 1><<<dim3(16, 32), 512, 0, stream>>>(
      y, w_outT, 4096, nullptr, nullptr, nullptr, out, x);
}